// Round 20
// baseline (572.744 us; speedup 1.0000x reference)
//
#include <hip/hip_runtime.h>
#include <stdint.h>

typedef unsigned short u16;
typedef __attribute__((ext_vector_type(2))) float f32x2;
typedef __attribute__((ext_vector_type(4))) float f32x4;
typedef __attribute__((ext_vector_type(4))) unsigned short u16x4;
typedef __attribute__((ext_vector_type(8))) short short8;

#define DEV static __device__ __forceinline__

DEV float bf2f(u16 u){ union{unsigned int i; float f;} v; v.i=((unsigned int)u)<<16; return v.f; }
DEV u16 f2bf(float f){ union{float f; unsigned int i;} v; v.f=f; unsigned int u=v.i;
  return (u16)((u + 0x7FFFu + ((u>>16)&1u))>>16); }
DEV float wred(float v){ for(int o=32;o;o>>=1) v += __shfl_xor(v,o); return v; }
DEV float wredmax(float v){ for(int o=32;o;o>>=1) v = fmaxf(v,__shfl_xor(v,o)); return v; }
DEV int wredi(int v){ for(int o=32;o;o>>=1) v += __shfl_xor(v,o); return v; }

DEV void gload16(const void* g, void* l){
  __builtin_amdgcn_global_load_lds((const __attribute__((address_space(1))) unsigned int*)g,
                                   (__attribute__((address_space(3))) unsigned int*)l, 16, 0, 0);
}

DEV float actf(int ACT, float v){
  if(ACT==1) return v>0.f?v:0.f;
  if(ACT==2) return 1.f/(1.f+__expf(-v));
  if(ACT==3) return tanhf(v);
  if(ACT==4) return v>0.f?v:(__expf(v)-1.f);
  return v;
}

// ---------------- f32 -> bf16 conversions ----------------
__global__ void cvt_kernel(const float* __restrict__ s, u16* __restrict__ d, int n4){
  for(int i=blockIdx.x*blockDim.x+threadIdx.x; i<n4; i+=gridDim.x*blockDim.x){
    f32x4 v=((const f32x4*)s)[i];
    u16x4 o;
    #pragma unroll
    for(int j=0;j<4;++j) o[j]=f2bf(v[j]);
    ((u16x4*)d)[i]=o;
  }
}

__global__ void cvt6_kernel(
    const float* __restrict__ s0, const float* __restrict__ s1, const float* __restrict__ s2,
    const float* __restrict__ s3, const float* __restrict__ s4, const float* __restrict__ s5,
    u16* __restrict__ d0, u16* __restrict__ d1, u16* __restrict__ d2,
    u16* __restrict__ d3, u16* __restrict__ d4, u16* __restrict__ d5, int n4each){
  const float* ss[6]={s0,s1,s2,s3,s4,s5};
  u16* dd[6]={d0,d1,d2,d3,d4,d5};
  const int total=6*n4each;
  for(int i=blockIdx.x*blockDim.x+threadIdx.x; i<total; i+=gridDim.x*blockDim.x){
    int b=i/n4each, r=i-b*n4each;
    f32x4 v=((const f32x4*)ss[b])[r];
    u16x4 o;
    #pragma unroll
    for(int j=0;j<4;++j) o[j]=f2bf(v[j]);
    ((u16x4*)dd[b])[r]=o;
  }
}

__global__ void cvt_split(const float* __restrict__ s, u16* __restrict__ hi, u16* __restrict__ lo, int n4){
  for(int i=blockIdx.x*blockDim.x+threadIdx.x; i<n4; i+=gridDim.x*blockDim.x){
    f32x4 v=((const f32x4*)s)[i];
    u16x4 h,l;
    #pragma unroll
    for(int j=0;j<4;++j){ h[j]=f2bf(v[j]); l[j]=f2bf(v[j]-bf2f(h[j])); }
    ((u16x4*)hi)[i]=h; ((u16x4*)lo)[i]=l;
  }
}

__global__ void cvt_split_rw1(const float* __restrict__ src, u16* __restrict__ hi, u16* __restrict__ lo){
  for(int i=blockIdx.x*blockDim.x+threadIdx.x; i<512*1024; i+=gridDim.x*blockDim.x){
    int r=i>>10, c=i&1023;
    float v=src[(size_t)r*1030+c];
    u16 h=f2bf(v);
    hi[i]=h; lo[i]=f2bf(v-bf2f(h));
  }
}

// transpose 1024x1024 f32 -> bf16: dst[j][i] = bf16(src[i][j])
__global__ __launch_bounds__(256) void transpose_bf(const float* __restrict__ src, u16* __restrict__ dst){
  __shared__ float t[32][33];
  const int bx=blockIdx.x&31, by=blockIdx.x>>5;
  const int lx=threadIdx.x&31, ly=threadIdx.x>>5;
  #pragma unroll
  for(int r=0;r<4;++r)
    t[ly+8*r][lx] = src[(size_t)(by*32+ly+8*r)*1024 + bx*32+lx];
  __syncthreads();
  #pragma unroll
  for(int r=0;r<4;++r)
    dst[(size_t)(bx*32+ly+8*r)*1024 + by*32+lx] = f2bf(t[lx][ly+8*r]);
}

// all small setup packs in one launch (grid 260 blocks x 256)
// blk 0..255: bias_comp rows; blk 256: b2816 tail (deg bias + b768); blk 257: b1024;
// blk 258-259: rw1t (3072 elems)
__global__ __launch_bounds__(256) void small_pack(
    const float* __restrict__ spo_w, const float* __restrict__ spv_b, const float* __restrict__ spo_b,
    const float* __restrict__ de_gb, const float* __restrict__ de_b1,
    const float* __restrict__ hf_b1, const float* __restrict__ lt_b1,
    const float* __restrict__ sim_b1, const float* __restrict__ rout_b1,
    const float* __restrict__ rout_w1,
    float* __restrict__ b2816, float* __restrict__ b1024, float* __restrict__ rw1t)
{
  const int b=blockIdx.x, tid=threadIdx.x;
  if(b<256){
    // bias_comp: bc[i] = spo_b[i] + spo_w[i,:].vb  -> b2816[0..1023]
    const int wv=tid>>6, lane=tid&63;
    const int rowi=b*4+wv;
    float s=0.f;
    const float* wr=spo_w+(size_t)rowi*1024;
    #pragma unroll
    for(int j=0;j<16;++j) s+=wr[j*64+lane]*spv_b[j*64+lane];
    s=wred(s);
    if(lane==0) b2816[rowi]=spo_b[rowi]+s;
  } else if(b==256){
    // b2816[1024..2047]=de_gb; [2048..2815]=b768
    for(int i=tid;i<1024;i+=256) b2816[1024+i]=de_gb[i];
    for(int i=tid;i<768;i+=256){
      float v = (i<256)? de_b1[i] : (i<512? hf_b1[i-256] : lt_b1[i-512]);
      b2816[2048+i]=v;
    }
  } else if(b==257){
    for(int i=tid;i<1024;i+=256) b1024[i]= (i<512)? sim_b1[i] : rout_b1[i-512];
  } else {
    int base=(b-258)*1536;
    for(int t=tid;t<1536;t+=256){
      int i=base+t;
      if(i<3072){
        int e=i>>9, col=i&511;
        rw1t[i]=rout_w1[(size_t)col*1030+1024+e];
      }
    }
  }
}

// ---------------- GEMM: fused epilogues, global_load_lds staging, XCD swizzle ----------
// EPI 0: C bf16 = v    1: C f32 = v    2: C bf16 = v*bf2f(auxb)
//     3: comb(bf16)  = w[0]*v
//     4: comb(bf16) += w[1]*(v + bf2f(auxb)*auxf)
//     5: comb(bf16) += w[3]*(x0 + (v-x0)*x0), x0=bf2f(auxb)
//     6: comb(bf16) += w[5]*sgn(x0)*sqrt(|v*x0|+1e-8), x0=bf2f(auxb)
//     7: C f32 = v + auxf (residual)
//     8: merged tri-output: col<1024 -> Cv bf16 = v*bf2f(auxb[row*1024+col])   (att*x)
//        col<2048 -> comb(as gate buf) bf16 = sigmoid(v) at [row*1024+col-1024]
//        col>=2048 -> auxg bf16 = act768(v) at [row*768+col-2048]
template<int ACT, int EPI>
__global__ __launch_bounds__(256) void gemm_bt(
    const u16* __restrict__ A, const u16* __restrict__ W,
    const float* __restrict__ bias, const u16* __restrict__ auxb,
    const float* __restrict__ auxf, const float* __restrict__ wsel,
    u16* __restrict__ comb, void* __restrict__ Cv, u16* __restrict__ auxg,
    int M, int N, int K, int lda)
{
  __shared__ __align__(16) u16 lA[128*64];
  __shared__ __align__(16) u16 lB[128*64];
  const int tid=threadIdx.x, lane=tid&63, wv=tid>>6;
  const int wr=wv>>1, wc=wv&1;
  const int gx=gridDim.x;
  const int nwg=gx*gridDim.y;
  const int flat=blockIdx.y*gx+blockIdx.x;
  const int chunk=nwg>>3;
  const int nf=(flat&7)*chunk + (flat>>3);
  const int bn=(nf%gx)*128, bm=(nf/gx)*128;
  f32x4 acc[4][4];
  #pragma unroll
  for(int m=0;m<4;++m){
    #pragma unroll
    for(int n=0;n<4;++n) acc[m][n]=(f32x4)0.f;
  }
  const int srow = wv*8 + (lane>>3);
  const int scol = (lane&7)*8;
  for(int kt=0;kt<K;kt+=64){
    #pragma unroll
    for(int i=0;i<4;++i){
      gload16(A + (size_t)(bm + i*32 + srow)*lda + kt + scol, &lA[(i*32 + wv*8)*64]);
      gload16(W + (size_t)(bn + i*32 + srow)*K + kt + scol, &lB[(i*32 + wv*8)*64]);
    }
    __syncthreads();
    #pragma unroll
    for(int kk=0;kk<2;++kk){
      const int fr=lane&15, kc=kk*32+(lane>>4)*8;
      short8 af[4], bfr[4];
      #pragma unroll
      for(int m=0;m<4;++m) af[m]=*(const short8*)&lA[(wr*64+m*16+fr)*64+kc];
      #pragma unroll
      for(int n=0;n<4;++n) bfr[n]=*(const short8*)&lB[(wc*64+n*16+fr)*64+kc];
      #pragma unroll
      for(int m=0;m<4;++m){
        #pragma unroll
        for(int n=0;n<4;++n)
          acc[m][n]=__builtin_amdgcn_mfma_f32_16x16x32_bf16(af[m],bfr[n],acc[m][n],0,0,0);
      }
    }
    __syncthreads();
  }
  const int fr=lane&15, fq=lane>>4;
  #pragma unroll
  for(int m=0;m<4;++m){
    #pragma unroll
    for(int n=0;n<4;++n){
      const int col = bn + wc*64 + n*16 + fr;
      const float bv = bias ? bias[col] : 0.f;
      #pragma unroll
      for(int j=0;j<4;++j){
        const int row = bm + wr*64 + m*16 + fq*4 + j;
        const size_t idx = (size_t)row*N+col;
        float v = acc[m][n][j] + bv;
        if(ACT==5){
          v = (col<256) ? fmaxf(v,0.f) : (col<512 ? tanhf(v) : (v>0.f?v:(__expf(v)-1.f)));
        } else v = actf(ACT, v);
        if(EPI==0){ ((u16*)Cv)[idx]=f2bf(v); }
        else if(EPI==1){ ((float*)Cv)[idx]=v; }
        else if(EPI==2){ ((u16*)Cv)[idx]=f2bf(v*bf2f(auxb[idx])); }
        else if(EPI==3){ comb[idx]=f2bf(wsel[row*6+0]*v); }
        else if(EPI==4){ comb[idx]=f2bf(bf2f(comb[idx])+wsel[row*6+1]*(v + bf2f(auxb[idx])*auxf[idx])); }
        else if(EPI==5){ float x0=bf2f(auxb[idx]); comb[idx]=f2bf(bf2f(comb[idx])+wsel[row*6+3]*(x0+(v-x0)*x0)); }
        else if(EPI==6){
          float x0=bf2f(auxb[idx]);
          float sg=(x0>0.f)?1.f:((x0<0.f)?-1.f:0.f);
          comb[idx]=f2bf(bf2f(comb[idx])+wsel[row*6+5]*sg*sqrtf(fabsf(v*x0)+1e-8f));
        }
        else if(EPI==7){ ((float*)Cv)[idx]=v+auxf[idx]; }
        else { // EPI 8: merged tri-output
          if(col<1024){
            size_t i1=(size_t)row*1024+col;
            ((u16*)Cv)[i1]=f2bf(v*bf2f(auxb[i1]));
          } else if(col<2048){
            size_t i1=(size_t)row*1024+(col-1024);
            comb[i1]=f2bf(1.f/(1.f+__expf(-v)));
          } else {
            int c7=col-2048;
            float a = (c7<256) ? fmaxf(v,0.f) : (c7<512 ? tanhf(v) : (v>0.f?v:(__expf(v)-1.f)));
            auxg[(size_t)row*768+c7]=f2bf(a);
          }
        }
      }
    }
  }
}

// ---------------- merged split-precision GEMM (3-term), 128x128 tile, XCD swizzle ------
__global__ __launch_bounds__(256) void gemm_split2(
    const u16* __restrict__ Ah, const u16* __restrict__ Al,
    const u16* __restrict__ Wh, const u16* __restrict__ Wl,
    const float* __restrict__ bias, float* __restrict__ C, int M, int N, int K)
{
  const int LDL=40;
  __shared__ __align__(16) u16 lAh[128*40], lAl[128*40], lBh[128*40], lBl[128*40];
  const int tid=threadIdx.x, lane=tid&63, wv=tid>>6;
  const int wr=wv>>1, wc=wv&1;
  const int nwg=gridDim.x;
  const int wg=(blockIdx.x%8)*(nwg/8)+blockIdx.x/8;
  const int bx=wg&7, by=wg>>3;
  const int bn=bx*128, bm=by*128;
  f32x4 acc[4][4];
  #pragma unroll
  for(int m=0;m<4;++m){
    #pragma unroll
    for(int n=0;n<4;++n) acc[m][n]=(f32x4)0.f;
  }
  const int srow=tid>>2, scol=(tid&3)*8;
  for(int kt=0;kt<K;kt+=32){
    short8 rah[2],ral[2],rbh[2],rbl[2];
    #pragma unroll
    for(int i=0;i<2;++i){
      size_t ao=(size_t)(bm+i*64+srow)*K+kt+scol;
      size_t bo=(size_t)(bn+i*64+srow)*K+kt+scol;
      rah[i]=*(const short8*)(Ah+ao); ral[i]=*(const short8*)(Al+ao);
      rbh[i]=*(const short8*)(Wh+bo); rbl[i]=*(const short8*)(Wl+bo);
    }
    __syncthreads();
    #pragma unroll
    for(int i=0;i<2;++i){
      int d=(i*64+srow)*LDL+scol;
      *(short8*)&lAh[d]=rah[i]; *(short8*)&lAl[d]=ral[i];
      *(short8*)&lBh[d]=rbh[i]; *(short8*)&lBl[d]=rbl[i];
    }
    __syncthreads();
    const int fr=lane&15, kc=(lane>>4)*8;
    short8 ah[4],al[4],bh[4],bl[4];
    #pragma unroll
    for(int m=0;m<4;++m){ int r=(wr*64+m*16+fr)*LDL+kc; ah[m]=*(const short8*)&lAh[r]; al[m]=*(const short8*)&lAl[r]; }
    #pragma unroll
    for(int n=0;n<4;++n){ int r=(wc*64+n*16+fr)*LDL+kc; bh[n]=*(const short8*)&lBh[r]; bl[n]=*(const short8*)&lBl[r]; }
    #pragma unroll
    for(int m=0;m<4;++m){
      #pragma unroll
      for(int n=0;n<4;++n){
        acc[m][n]=__builtin_amdgcn_mfma_f32_16x16x32_bf16(ah[m],bh[n],acc[m][n],0,0,0);
        acc[m][n]=__builtin_amdgcn_mfma_f32_16x16x32_bf16(ah[m],bl[n],acc[m][n],0,0,0);
        acc[m][n]=__builtin_amdgcn_mfma_f32_16x16x32_bf16(al[m],bh[n],acc[m][n],0,0,0);
      }
    }
  }
  const int fr=lane&15, fq=lane>>4;
  #pragma unroll
  for(int m=0;m<4;++m){
    #pragma unroll
    for(int n=0;n<4;++n){
      const int col = bn + wc*64 + n*16 + fr;
      const float bv = bias[col];
      #pragma unroll
      for(int j=0;j<4;++j){
        const int row = bm + wr*64 + m*16 + fq*4 + j;
        float v = acc[m][n][j] + bv;
        if(col<512) v=fmaxf(v,0.f);
        C[(size_t)row*N+col] = v;
      }
    }
  }
}

// ---------------- feats + x split: one wave/row, barrier-free; also emits x_hi/x_lo ----
__global__ __launch_bounds__(256) void feats_kernel(const float* __restrict__ x,
    const float* __restrict__ kw1, const float* __restrict__ kb1,
    const float* __restrict__ kw2, const float* __restrict__ kb2,
    float* __restrict__ kvals, u16* __restrict__ x_hi, u16* __restrict__ x_lo)
{
  const int lane=threadIdx.x&63, wv=threadIdx.x>>6;
  const int row=blockIdx.x*4+wv;
  const float* xr=x+(size_t)row*1024;
  u16x4* hio=(u16x4*)(x_hi+(size_t)row*1024);
  u16x4* loo=(u16x4*)(x_lo+(size_t)row*1024);
  float xv[16]; unsigned int cd[16];
  float s=0.f, ss=0.f, sa=0.f, nz=0.f, amax=0.f;
  #pragma unroll
  for(int t=0;t<4;++t){
    f32x4 v=((const f32x4*)xr)[t*64+lane];
    u16x4 h,l;
    #pragma unroll
    for(int j=0;j<4;++j){
      float f=v[j];
      union{float f;unsigned int i;} c; c.f=f;
      xv[t*4+j]=f; cd[t*4+j]=c.i&0x7fffffffu;
      h[j]=f2bf(f); l[j]=f2bf(f-bf2f(h[j]));
      s+=f; ss+=f*f; float a=fabsf(f); sa+=a; amax=fmaxf(amax,a); if(f==0.f) nz+=1.f;
    }
    hio[t*64+lane]=h; loo[t*64+lane]=l;
  }
  s=wred(s); ss=wred(ss); sa=wred(sa); nz=wred(nz); amax=wredmax(amax);
  const float mean=s/1024.f;
  const float var=(ss - s*mean)/1023.f;
  const float inv=1.f/sqrtf(var+1e-8f);
  float sk=0.f;
  #pragma unroll
  for(int j=0;j<16;++j){ float z=(xv[j]-mean)*inv; sk+=z*z*z; }
  sk=wred(sk);
  unsigned int lo=0u, hi=0x7f800000u;
  while(hi-lo>1u){
    unsigned int mid=(lo+hi)>>1;
    int c=0;
    #pragma unroll
    for(int j=0;j<16;++j) c += (cd[j] >= mid);
    c=wredi(c);
    if(c>=204) lo=mid; else hi=mid;
  }
  const unsigned int T=lo;
  float sg=0.f, cg=0.f;
  #pragma unroll
  for(int j=0;j<16;++j){ if(cd[j] > T){ sg+=fabsf(xv[j]); cg+=1.f; } }
  sg=wred(sg); cg=wred(cg);
  if(lane==0){
    union{unsigned int i;float f;} tv; tv.i=T;
    float conc=(sg + (204.f-cg)*tv.f)/(sa + 1e-8f);
    float feats[6]={ nz/1024.f, var, amax, sqrtf(ss), sk/1024.f, conc };
    float out=kb2[0];
    #pragma unroll
    for(int i=0;i<16;++i){
      float hv=kb1[i];
      #pragma unroll
      for(int j=0;j<6;++j) hv+=kw1[i*6+j]*feats[j];
      hv=fmaxf(hv,0.f);
      out+=kw2[i]*hv;
    }
    kvals[row]=1.f + 3.f*(1.f/(1.f+__expf(-out)));
  }
}

// ---------------- exact median of 8192 -> k (radix select x2, per-wave hist) -----------
__global__ __launch_bounds__(256) void median_kernel(const float* __restrict__ kvals, int* __restrict__ kint){
  __shared__ unsigned int v[8192];
  __shared__ int hist4[4*257];
  __shared__ unsigned int selT;
  __shared__ int selR;
  const int tid=threadIdx.x, lane=tid&63, wv=tid>>6;
  for(int i=tid;i<8192;i+=256){ union{float f;unsigned int u;} c; c.f=kvals[i]; v[i]=c.u; }
  __syncthreads();
  unsigned int res[2];
  for(int t=0;t<2;++t){
    int r = 8192 - (4096+t) + 1;
    unsigned int prefix=0u;
    for(int lvl=0;lvl<4;++lvl){
      const int shift=24-lvl*8;
      const unsigned int pmask = (lvl==0)?0u:(0xFFFFFFFFu<<(shift+8));
      for(int i=tid;i<4*257;i+=256) hist4[i]=0;
      __syncthreads();
      for(int i=tid;i<8192;i+=256){
        unsigned int c=v[i];
        if((c&pmask)==prefix) atomicAdd(&hist4[wv*257+((c>>shift)&0xFFu)],1);
      }
      __syncthreads();
      if(wv==0){
        int h[4]; int ls=0;
        #pragma unroll
        for(int b=0;b<4;++b){
          int bin=lane*4+b;
          h[b]=hist4[bin]+hist4[257+bin]+hist4[514+bin]+hist4[771+bin];
          ls+=h[b];
        }
        int pfx=ls;
        #pragma unroll
        for(int off=1;off<64;off<<=1){ int tt=__shfl_up(pfx,off); if(lane>=off) pfx+=tt; }
        int total=__shfl(pfx,63);
        int cgt = total - pfx;
        #pragma unroll
        for(int b=3;b>=0;--b){
          if(cgt < r && r <= cgt + h[b]){
            selT = prefix | ((unsigned int)(lane*4+b)<<shift);
            selR = r - cgt;
          }
          cgt += h[b];
        }
      }
      __syncthreads();
      prefix=selT; r=selR;
      __syncthreads();
    }
    res[t]=prefix;
  }
  if(tid==0){
    union{unsigned int u; float f;} a,b; a.u=res[0]; b.u=res[1];
    float med=0.5f*(a.f+b.f);
    int k=(int)floorf(med);
    k = k<1?1:(k>4?4:k);
    *kint=k;
  }
}

// ---------------- fused router: spec -> h-tail fix -> probs -> top-k gates -> wsel -----
__global__ __launch_bounds__(256) void router_kernel(const float* __restrict__ x,
    const float* __restrict__ h, const float* __restrict__ esp,
    const float* __restrict__ w2s, const float* __restrict__ b2s,
    const float* __restrict__ rw1t, const float* __restrict__ w2r,
    const float* __restrict__ b2r, const int* __restrict__ kint,
    float* __restrict__ wsel)
{
  const int wv=threadIdx.x>>6, lane=threadIdx.x&63;
  const int row=blockIdx.x*4+wv;
  const float* xr=x+(size_t)row*1024;
  const float* hr=h+(size_t)row*1024;
  float xv[16], h0[8], h1[8];
  #pragma unroll
  for(int j=0;j<16;++j) xv[j]=xr[j*64+lane];
  #pragma unroll
  for(int j=0;j<8;++j){ h0[j]=hr[j*64+lane]; h1[j]=hr[512+j*64+lane]; }
  float spec[6];
  #pragma unroll
  for(int e=0;e<6;++e){
    float s=0.f;
    #pragma unroll
    for(int j=0;j<16;++j) s+=xv[j]*esp[e*1024+j*64+lane];
    #pragma unroll
    for(int j=0;j<8;++j) s+=h0[j]*w2s[e*512+j*64+lane];
    s=wred(s);
    spec[e]=1.f/(1.f+__expf(-(s+b2s[e])));
  }
  #pragma unroll
  for(int e=0;e<6;++e){
    const float se=spec[e];
    #pragma unroll
    for(int j=0;j<8;++j) h1[j]+=se*rw1t[e*512+j*64+lane];
  }
  #pragma unroll
  for(int j=0;j<8;++j) h1[j]=fmaxf(h1[j],0.f);
  float p[6];
  float m=-1e30f;
  #pragma unroll
  for(int e=0;e<6;++e){
    float s=0.f;
    #pragma unroll
    for(int j=0;j<8;++j) s+=h1[j]*w2r[e*512+j*64+lane];
    p[e]=wred(s)+b2r[e];
    m=fmaxf(m,p[e]);
  }
  float den=0.f;
  #pragma unroll
  for(int e=0;e<6;++e){ p[e]=__expf(p[e]-m); den+=p[e]; }
  float invd=1.f/den;
  #pragma unroll
  for(int e=0;e<6;++e) p[e]*=invd;
  if(lane==0){
    const int k=*kint;
    float w[6]={0,0,0,0,0,0};
    bool used[6]={false,false,false,false,false,false};
    int idx[4]; float val[4];
    #pragma unroll
    for(int j=0;j<4;++j){
      int bi=0; float bv=-1e30f;
      #pragma unroll
      for(int e=0;e<6;++e) if(!used[e] && p[e]>bv){ bv=p[e]; bi=e; }
      used[bi]=true; idx[j]=bi; val[j]=bv;
    }
    float mm=val[0], dd=0.f, g[4]={0,0,0,0};
    for(int j=0;j<k;++j){ g[j]=__expf(val[j]-mm); dd+=g[j]; }
    for(int j=0;j<k;++j) w[idx[j]]=g[j]/dd;
    float* o=&wsel[(size_t)row*6];
    o[0]=w[0]; o[1]=w[1]; o[2]=w[2]; o[3]=w[3]; o[4]=w[4]; o[5]=w[5];
  }
}

// ---------------- CrossField expert: MFMA, 1 wave/row, 4 rows/block, bf16 comb ---------
__global__ __launch_bounds__(256) void cf_kernel(const float* __restrict__ x,
    const float* __restrict__ w_in, const float* __restrict__ b_in,
    const float* __restrict__ w_o, const float* __restrict__ b_o,
    const float* __restrict__ w_f, const float* __restrict__ b_f,
    const float* __restrict__ wsel, u16* __restrict__ comb){
  __shared__ __align__(16) u16 smem[6400 + 4*6144];
  const int tid=threadIdx.x, wv=tid>>6, lane=tid&63;
  const int fr=lane&15, fq=lane>>4;
  for(int i=tid;i<5120;i+=256){
    float v=(i<3072)? w_in[i] : (i<4096? w_o[i-3072] : w_f[i-4096]);
    smem[(i>>5)*40 + (i&31)] = f2bf(v);
  }
  u16* wb   = smem + 6400 + wv*6144;
  float* xfl= (float*)wb;
  u16* bufA = wb + 2304;
  u16* bufB = bufA + 1280;
  u16* bufC = bufB + 1280;
  const int row = blockIdx.x*4 + wv;
  const float* xr = x + (size_t)row*1024;
  #pragma unroll
  for(int t=0;t<4;++t){
    f32x4 v = ((const f32x4*)xr)[t*64+lane];
    int e=(t*64+lane)*4;
    *(f32x4*)&xfl[(e>>5)*36 + (e&31)] = v;
  }
  __syncthreads();
  short8 xa[2];
  #pragma unroll
  for(int ft=0;ft<2;++ft){
    f32x4 a=*(const f32x4*)&xfl[(ft*16+fr)*36 + fq*8];
    f32x4 b=*(const f32x4*)&xfl[(ft*16+fr)*36 + fq*8 + 4];
    short8 s;
    s[0]=(short)f2bf(a[0]); s[1]=(short)f2bf(a[1]); s[2]=(short)f2bf(a[2]); s[3]=(short)f2bf(a[3]);
    s[4]=(short)f2bf(b[0]); s[5]=(short)f2bf(b[1]); s[6]=(short)f2bf(b[2]); s[7]=(short)f2bf(b[3]);
    xa[ft]=s;
  }
  f32x4 acc1[2][6];
  #pragma unroll
  for(int ct=0;ct<6;++ct){
    short8 wfrag=*(const short8*)&smem[(ct*16+fr)*40 + fq*8];
    #pragma unroll
    for(int ft=0;ft<2;++ft)
      acc1[ft][ct]=__builtin_amdgcn_mfma_f32_16x16x32_bf16(xa[ft],wfrag,(f32x4)0.f,0,0,0);
  }
  float bi[6];
  #pragma unroll
  for(int ct=0;ct<6;++ct) bi[ct]=b_in[ct*16+fr];
  #pragma unroll
  for(int ct=0;ct<6;++ct){
    #pragma unroll
    for(int ft=0;ft<2;++ft){
      #pragma unroll
      for(int j=0;j<4;++j){
        u16 h=f2bf(acc1[ft][ct][j]+bi[ct]);
        int rg=ft*16+fq*4+j, cg=ct*16+fr;
        if(cg<32)      bufA[rg*40+cg]=h;
        else if(cg<64) bufB[rg*40+(cg-32)]=h;
        else           bufC[(cg-64)*40+rg]=h;
      }
    }
  }
  __syncthreads();
  short8 qa0=*(const short8*)&bufA[fr*40+fq*8];
  short8 qa1=*(const short8*)&bufA[(16+fr)*40+fq*8];
  short8 kb0=*(const short8*)&bufB[fr*40+fq*8];
  short8 kb1=*(const short8*)&bufB[(16+fr)*40+fq*8];
  f32x4 aS[2][2];
  aS[0][0]=__builtin_amdgcn_mfma_f32_16x16x32_bf16(qa0,kb0,(f32x4)0.f,0,0,0);
  aS[0][1]=__builtin_amdgcn_mfma_f32_16x16x32_bf16(qa0,kb1,(f32x4)0.f,0,0,0);
  aS[1][0]=__builtin_amdgcn_mfma_f32_16x16x32_bf16(qa1,kb0,(f32x4)0.f,0,0,0);
  aS[1][1]=__builtin_amdgcn_mfma_f32_16x16x32_bf16(qa1,kb1,(f32x4)0.f,0,0,0);
  const float scale=0.17677669529663687f;
  #pragma unroll
  for(int rt=0;rt<2;++rt){
    #pragma unroll
    for(int j=0;j<4;++j){
      float e0=aS[rt][0][j]*scale, e1=aS[rt][1][j]*scale;
      float m=fmaxf(e0,e1);
      #pragma unroll
      for(int o=1;o<16;o<<=1) m=fmaxf(m,__shfl_xor(m,o));
      e0=__expf(e0-m); e1=__expf(e1-m);
      float den=e0+e1;
      #pragma unroll
      for(int o=1;o<16;o<<=1) den+=__shfl_xor(den,o);
      float inv=1.f/den;
      bufA[(rt*16+fq*4+j)*40 + fr]      = f2bf(e0*inv);
      bufA[(rt*16+fq*4+j)*40 + 16+fr]   = f2bf(e1*inv);
    }
  }
  __syncthreads();
  short8 pa0=*(const short8*)&bufA[fr*40+fq*8];
  short8 pa1=*(const short8*)&bufA[(16+fr)*40+fq*8];
  short8 vb0=*(const short8*)&bufC[fr*40+fq*8];
  short8 vb1=*(const short8*)&bufC[(16+fr)*40+fq*8];
  f32x4 aA[2][2];
  aA[0][0]=__builtin_amdgcn_mfma_f32_16x16x32_bf16(pa0,vb0,(f32x4)0.f,0,0,0);
  aA[0][1]=__builtin_amdgcn_mfma_f32_16x16x32_bf16(pa0,vb1,(f32x4)0.f,0,0,0);
  aA[1][0]=__builtin_amdgcn_mfma_f32_16x16x32_bf16(pa1,vb0,(f32x4)0.f,0,0,0);
  aA[1][1]=__builtin_amdgcn_mfma_f32_16x16x32_bf16(pa1,vb1,(f32x4)0.f,0,0,0);
  #pragma unroll
  for(int rt=0;rt<2;++rt)
    #pragma unroll
    for(int dt=0;dt<2;++dt)
      #pragma unroll
      for(int j=0;j<4;++j)
        bufB[(rt*16+fq*4+j)*40 + dt*16+fr]=f2bf(aA[rt][dt][j]);
  __syncthreads();
  short8 aa0=*(const short8*)&bufB[fr*40+fq*8];
  short8 aa1=*(const short8*)&bufB[(16+fr)*40+fq*8];
  short8 ob0=*(const short8*)&smem[(96+fr)*40+fq*8];
  short8 ob1=*(const short8*)&smem[(112+fr)*40+fq*8];
  f32x4 aF[2][2];
  aF[0][0]=__builtin_amdgcn_mfma_f32_16x16x32_bf16(aa0,ob0,(f32x4)0.f,0,0,0);
  aF[0][1]=__builtin_amdgcn_mfma_f32_16x16x32_bf16(aa0,ob1,(f32x4)0.f,0,0,0);
  aF[1][0]=__builtin_amdgcn_mfma_f32_16x16x32_bf16(aa1,ob0,(f32x4)0.f,0,0,0);
  aF[1][1]=__builtin_amdgcn_mfma_f32_16x16x32_bf16(aa1,ob1,(f32x4)0.f,0,0,0);
  float bo[2]={b_o[fr], b_o[16+fr]};
  #pragma unroll
  for(int rt=0;rt<2;++rt){
    #pragma unroll
    for(int dt=0;dt<2;++dt){
      #pragma unroll
      for(int j=0;j<4;++j){
        int fld=rt*16+fq*4+j, d=dt*16+fr;
        float attf=aF[rt][dt][j]+bo[dt];
        bufC[fld*40+d]=f2bf(attf*xfl[fld*36+d]);
      }
    }
  }
  __syncthreads();
  short8 pr0=*(const short8*)&bufC[fr*40+fq*8];
  short8 pr1=*(const short8*)&bufC[(16+fr)*40+fq*8];
  short8 fb0=*(const short8*)&smem[(128+fr)*40+fq*8];
  short8 fb1=*(const short8*)&smem[(144+fr)*40+fq*8];
  f32x4 aE[2][2];
  aE[0][0]=__builtin_amdgcn_mfma_f32_16x16x32_bf16(pr0,fb0,(f32x4)0.f,0,0,0);
  aE[0][1]=__builtin_amdgcn_mfma_f32_16x16x32_bf16(pr0,fb1,(f32x4)0.f,0,0,0);
  aE[1][0]=__builtin_amdgcn_mfma_f32_16x16x32_bf16(pr1,fb0,(f32x4)0.f,0,0,0);
  aE[1][1]=__builtin_amdgcn_mfma_f32_16x16x32_bf16(pr1,fb1,(f32x4)0.f,0,0,0);
  float bff[2]={b_f[fr], b_f[16+fr]};
  const float w2=wsel[row*6+2];
  u16* cb=&comb[(size_t)row*1024];
  #pragma unroll
  for(int rt=0;rt<2;++rt){
    #pragma unroll
    for(int dt=0;dt<2;++dt){
      #pragma unroll
      for(int j=0;j<4;++j){
        int fld=rt*16+fq*4+j, d=dt*16+fr;
        u16 old=cb[fld*32+d];
        cb[fld*32+d]=f2bf(bf2f(old)+w2*(aE[rt][dt][j]+bff[dt]));
      }
    }
  }
}

// ---------------- Temporal expert + final bf16 conversion (bf16 comb) -------------------
__global__ __launch_bounds__(256) void tp_kernel(const float* __restrict__ x,
    const float* __restrict__ wsel, const u16* __restrict__ comb,
    const float* __restrict__ tcw, const float* __restrict__ tcb,
    const float* __restrict__ tfw, const float* __restrict__ tfb,
    u16* __restrict__ obf){
  __shared__ float xs[1026];
  const int row=blockIdx.x, tid=threadIdx.x;
  f32x4 u=((const f32x4*)(x+(size_t)row*1024))[tid];
  #pragma unroll
  for(int j=0;j<4;++j) xs[1+4*tid+j]=u[j];
  if(tid==0){ xs[0]=0.f; xs[1025]=0.f; }
  __syncthreads();
  const float w4=wsel[row*6+4];
  float tc[4][3], tb[4], tf[4];
  #pragma unroll
  for(int o=0;o<4;++o){
    #pragma unroll
    for(int kh=0;kh<3;++kh) tc[o][kh]=tcw[o*3+kh];
    tb[o]=tcb[o]; tf[o]=tfw[o];
  }
  const float tfb0=tfb[0];
  u16x4 cv=((const u16x4*)(comb+(size_t)row*1024))[tid];
  u16x4 ov;
  #pragma unroll
  for(int j=0;j<4;++j){
    const int d=4*tid+j;
    float pre=tfb0;
    #pragma unroll
    for(int o=0;o<4;++o){
      float c=tb[o]+tc[o][0]*xs[d]+tc[o][1]*xs[d+1]+tc[o][2]*xs[d+2];
      pre+=tf[o]*fmaxf(c,0.f);
    }
    float wt=1.f/(1.f+__expf(-pre));
    float xv=xs[1+d];
    ov[j]=f2bf(bf2f(cv[j])+w4*xv*xv*wt);
  }
  ((u16x4*)(obf+(size_t)row*1024))[tid]=ov;
}

// =======================================================================================
extern "C" void kernel_launch(void* const* d_in, const int* in_sizes, int n_in,
                              void* d_out, int out_size, void* d_ws, size_t ws_size,
                              hipStream_t stream)
{
  const float* x     =(const float*)d_in[0];
  const float* esp   =(const float*)d_in[1];
  const float* sim_w1=(const float*)d_in[2],  *sim_b1=(const float*)d_in[3];
  const float* sim_w2=(const float*)d_in[4],  *sim_b2=(const float*)d_in[5];
  const float* rout_w1=(const float*)d_in[6], *rout_b1=(const float*)d_in[7];
  const float* rout_w2=(const float*)d_in[8], *rout_b2=(const float*)d_in[9];
  const float* kw1=(const float*)d_in[10], *kb1=(const float*)d_in[11];
  const float* kw2=(const float*)d_in[12], *kb2=(const float*)d_in[13];
  const float* spv_w=(const float*)d_in[14], *spv_b=(const float*)d_in[15];
  const float* spo_w=(const float*)d_in[16], *spo_b=(const float*)d_in[17];
  const float* spq1_w=(const float*)d_in[18], *spq1_b=(const float*)d_in[19];
  const float* spq2_w=(const float*)d_in[20], *spq2_b=(const float*)d_in[21];
  const float* de_w1=(const float*)d_in[22], *de_b1=(const float*)d_in[23];
  const float* de_w2=(const float*)d_in[24], *de_b2=(const float*)d_in[25];
  const float* de_gw=(const float*)d_in[26], *de_gb=(const float*)d_in[27];
  const float* cf_inw=(const float*)d_in[28], *cf_inb=(const float*)d_in[29];
  const float* cf_ow=(const float*)d_in[30], *cf_ob=(const float*)d_in[31];
  const float* cf_fw=(const float*)d_in[32], *cf_fb=(const float*)d_in[33];
  const float* hf_w1=(const float*)d_in[34], *hf_b1=(const float*)d_in[35];
  const float* hf_w2=(const float*)d_in[36], *hf_b2=(const float*)d_in[37];
  const float* tc_w=(const float*)d_in[38], *tc_b=(const float*)d_in[39];
  const float* tf_w=(const float*)d_in[40], *tf_b=(const float*)d_in[41];
  const float* lt_w1=(const float*)d_in[42], *lt_b1=(const float*)d_in[43];
  const float* lt_w2=(const float*)d_in[44], *lt_b2=(const float*)d_in[45];
  const float* op_w=(const float*)d_in[46], *op_b=(const float*)d_in[47];
  float* out=(float*)d_out;
  (void)in_sizes; (void)n_in; (void)out_size; (void)ws_size;

  constexpr int NB=8192;
  const size_t BD=(size_t)NB*1024;
  char* base=(char*)d_ws; size_t off=0;
  auto carve=[&](size_t n)->void*{ void* q=base+off; off+=(n+255)&~(size_t)255; return q; };
  u16*  comb =(u16*)carve(BD*2);
  u16*  bufA =(u16*)carve(BD*2);
  u16*  bufB =(u16*)carve(BD*2);
  u16*  gate =(u16*)carve(BD*2);
  u16*  x_hi =(u16*)carve(BD*2);
  u16*  x_lo =(u16*)carve(BD*2);
  float* h1024=(float*)carve(BD*4);
  u16*  h768 =(u16*)carve((size_t)NB*768*2);
  u16* w1024h=(u16*)carve((size_t)1024*1024*2);
  u16* w1024l=(u16*)carve((size_t)1024*1024*2);
  u16* wBig  =(u16*)carve((size_t)2816*1024*2);   // [Wc | degw | w768]
  u16* spo_bf =(u16*)carve((size_t)1024*1024*2);
  u16* spq1_bf=(u16*)carve((size_t)1024*1024*2);
  u16* spq2_bf=(u16*)carve((size_t)1024*1024*2);
  u16* dew2_bf=(u16*)carve((size_t)1024*256*2);
  u16* hfw2_bf=(u16*)carve((size_t)1024*256*2);
  u16* ltw2_bf=(u16*)carve((size_t)1024*256*2);
  u16* opw_bf =(u16*)carve((size_t)1024*1024*2);
  u16* spvT_bf=(u16*)carve((size_t)1024*1024*2);
  float* b2816=(float*)carve((size_t)2816*4);
  float* b1024=(float*)carve((size_t)1024*4);
  float* rw1t =(float*)carve((size_t)3072*4);
  float* wsel=(float*)carve((size_t)NB*6*4);
  float* kvals=(float*)carve((size_t)NB*4);
  int*   kint=(int*)carve(256);

  const dim3 blk(256);
  auto cgrid=[&](int n4)->dim3{ int g=(n4+255)/256; return dim3(g>2048?2048:g); };

  // ---- feats + x split (x read once) ----
  feats_kernel<<<dim3(2048),blk,0,stream>>>(x, kw1,kb1,kw2,kb2, kvals, x_hi, x_lo);
  median_kernel<<<dim3(1),blk,0,stream>>>(kvals, kint);

  // ---- weight conversions (batched) ----
  cvt_split<<<cgrid(131072),blk,0,stream>>>(sim_w1, w1024h, w1024l, 131072);
  cvt_split_rw1<<<cgrid(131072),blk,0,stream>>>(rout_w1, w1024h+524288, w1024l+524288);
  // degw -> wBig rows 1024..2047 ; w768 -> wBig rows 2048..2815
  cvt6_kernel<<<cgrid(6*262144),blk,0,stream>>>(spo_w,spq1_w,spq2_w,de_gw,op_w,spv_w,
                                                spo_bf,spq1_bf,spq2_bf,wBig+1048576,opw_bf,spvT_bf, 262144);
  // NOTE: spv_w conversion above into spvT_bf is a placeholder ordering; real transpose below overwrites it.
  cvt6_kernel<<<cgrid(6*65536),blk,0,stream>>>(de_w1,de_w2,hf_w1,hf_w2,lt_w1,lt_w2,
                                               wBig+2097152,dew2_bf,wBig+2097152+262144,hfw2_bf,wBig+2097152+524288,ltw2_bf, 65536);
  transpose_bf<<<dim3(1024),blk,0,stream>>>(spv_w, spvT_bf);
  small_pack<<<dim3(260),blk,0,stream>>>(spo_w, spv_b, spo_b, de_gb, de_b1, hf_b1, lt_b1,
                                         sim_b1, rout_b1, rout_w1, b2816, b1024, rw1t);

  // ---- routing pipeline (merged N=1024 split GEMM + fused router) ----
  gemm_split2<<<dim3(512),blk,0,stream>>>(x_hi,x_lo, w1024h,w1024l, b1024, h1024, NB,1024,1024);
  router_kernel<<<dim3(2048),blk,0,stream>>>(x, h1024, esp, sim_w2, sim_b2, rw1t, rout_w2, rout_b2, kint, wsel);

  // ---- compose Wc = spo_w @ spv_w -> wBig rows 0..1023 ----
  gemm_bt<0,1><<<dim3(8,8),blk,0,stream>>>(spo_bf, spvT_bf, nullptr, nullptr, nullptr, nullptr, nullptr, h1024, nullptr, 1024,1024,1024,1024);
  cvt_kernel<<<cgrid(262144),blk,0,stream>>>(h1024, wBig, 262144);

  // ---- merged tri-GEMM: att(bufB) | gate | h768  (one x_hi read) ----
  gemm_bt<0,8><<<dim3(22,64),blk,0,stream>>>(x_hi, wBig, b2816, x_hi, nullptr, nullptr, gate, bufB, h768, NB,2816,1024,1024);

  // ---- expert 0 remainder: spq1, spq2 ----
  gemm_bt<1,0><<<dim3(8,64),blk,0,stream>>>(bufB, spq1_bf, spq1_b, nullptr, nullptr, nullptr, nullptr, bufA, nullptr, NB,1024,1024,1024);
  gemm_bt<0,3><<<dim3(8,64),blk,0,stream>>>(bufA, spq2_bf, spq2_b, nullptr, nullptr, wsel, comb, nullptr, nullptr, NB,1024,1024,1024);

  // ---- expert 1: DenseQuadratic (gate precomputed) ----
  gemm_bt<0,4><<<dim3(8,64),blk,0,stream>>>(h768, dew2_bf, de_b2, gate, x, wsel, comb, nullptr, nullptr, NB,1024,256,768);

  // ---- expert 2: CrossField (MFMA, fused accumulate) ----
  cf_kernel<<<dim3(2048),blk,0,stream>>>(x, cf_inw, cf_inb, cf_ow, cf_ob, cf_fw, cf_fb, wsel, comb);

  // ---- expert 3: HighFreq ----
  gemm_bt<0,5><<<dim3(8,64),blk,0,stream>>>(h768+256, hfw2_bf, hf_b2, x_hi, nullptr, wsel, comb, nullptr, nullptr, NB,1024,256,768);

  // ---- expert 5: LongTail ----
  gemm_bt<0,6><<<dim3(8,64),blk,0,stream>>>(h768+512, ltw2_bf, lt_b2, x_hi, nullptr, wsel, comb, nullptr, nullptr, NB,1024,256,768);

  // ---- expert 4: Temporal (last comb reader) + final bf16 conversion ----
  tp_kernel<<<dim3(NB),blk,0,stream>>>(x, wsel, comb, tc_w, tc_b, tf_w, tf_b, bufB);

  // ---- output projection + residual (f32 out) ----
  gemm_bt<0,7><<<dim3(8,64),blk,0,stream>>>(bufB, opw_bf, op_b, nullptr, x, nullptr, nullptr, out, nullptr, NB,1024,1024,1024);
}

// Round 21
// 554.702 us; speedup vs baseline: 1.0325x; 1.0325x over previous
//
#include <hip/hip_runtime.h>
#include <stdint.h>

typedef unsigned short u16;
typedef __attribute__((ext_vector_type(2))) float f32x2;
typedef __attribute__((ext_vector_type(4))) float f32x4;
typedef __attribute__((ext_vector_type(4))) unsigned short u16x4;
typedef __attribute__((ext_vector_type(8))) short short8;

#define DEV static __device__ __forceinline__

DEV float bf2f(u16 u){ union{unsigned int i; float f;} v; v.i=((unsigned int)u)<<16; return v.f; }
DEV u16 f2bf(float f){ union{float f; unsigned int i;} v; v.f=f; unsigned int u=v.i;
  return (u16)((u + 0x7FFFu + ((u>>16)&1u))>>16); }
DEV float wred(float v){ for(int o=32;o;o>>=1) v += __shfl_xor(v,o); return v; }
DEV float wredmax(float v){ for(int o=32;o;o>>=1) v = fmaxf(v,__shfl_xor(v,o)); return v; }
DEV int wredi(int v){ for(int o=32;o;o>>=1) v += __shfl_xor(v,o); return v; }

DEV void gload16(const void* g, void* l){
  __builtin_amdgcn_global_load_lds((const __attribute__((address_space(1))) unsigned int*)g,
                                   (__attribute__((address_space(3))) unsigned int*)l, 16, 0, 0);
}

DEV float actf(int ACT, float v){
  if(ACT==1) return v>0.f?v:0.f;
  if(ACT==2) return 1.f/(1.f+__expf(-v));
  if(ACT==3) return tanhf(v);
  if(ACT==4) return v>0.f?v:(__expf(v)-1.f);
  return v;
}

// ---------------- f32 -> bf16 conversions ----------------
__global__ void cvt_kernel(const float* __restrict__ s, u16* __restrict__ d, int n4){
  for(int i=blockIdx.x*blockDim.x+threadIdx.x; i<n4; i+=gridDim.x*blockDim.x){
    f32x4 v=((const f32x4*)s)[i];
    u16x4 o;
    #pragma unroll
    for(int j=0;j<4;++j) o[j]=f2bf(v[j]);
    ((u16x4*)d)[i]=o;
  }
}

__global__ void cvt6_kernel(
    const float* __restrict__ s0, const float* __restrict__ s1, const float* __restrict__ s2,
    const float* __restrict__ s3, const float* __restrict__ s4, const float* __restrict__ s5,
    u16* __restrict__ d0, u16* __restrict__ d1, u16* __restrict__ d2,
    u16* __restrict__ d3, u16* __restrict__ d4, u16* __restrict__ d5, int n4each){
  const float* ss[6]={s0,s1,s2,s3,s4,s5};
  u16* dd[6]={d0,d1,d2,d3,d4,d5};
  const int total=6*n4each;
  for(int i=blockIdx.x*blockDim.x+threadIdx.x; i<total; i+=gridDim.x*blockDim.x){
    int b=i/n4each, r=i-b*n4each;
    f32x4 v=((const f32x4*)ss[b])[r];
    u16x4 o;
    #pragma unroll
    for(int j=0;j<4;++j) o[j]=f2bf(v[j]);
    ((u16x4*)dd[b])[r]=o;
  }
}

__global__ void cvt_split(const float* __restrict__ s, u16* __restrict__ hi, u16* __restrict__ lo, int n4){
  for(int i=blockIdx.x*blockDim.x+threadIdx.x; i<n4; i+=gridDim.x*blockDim.x){
    f32x4 v=((const f32x4*)s)[i];
    u16x4 h,l;
    #pragma unroll
    for(int j=0;j<4;++j){ h[j]=f2bf(v[j]); l[j]=f2bf(v[j]-bf2f(h[j])); }
    ((u16x4*)hi)[i]=h; ((u16x4*)lo)[i]=l;
  }
}

__global__ void cvt_split_rw1(const float* __restrict__ src, u16* __restrict__ hi, u16* __restrict__ lo){
  for(int i=blockIdx.x*blockDim.x+threadIdx.x; i<512*1024; i+=gridDim.x*blockDim.x){
    int r=i>>10, c=i&1023;
    float v=src[(size_t)r*1030+c];
    u16 h=f2bf(v);
    hi[i]=h; lo[i]=f2bf(v-bf2f(h));
  }
}

// transpose 1024x1024 f32 -> bf16: dst[j][i] = bf16(src[i][j])
__global__ __launch_bounds__(256) void transpose_bf(const float* __restrict__ src, u16* __restrict__ dst){
  __shared__ float t[32][33];
  const int bx=blockIdx.x&31, by=blockIdx.x>>5;
  const int lx=threadIdx.x&31, ly=threadIdx.x>>5;
  #pragma unroll
  for(int r=0;r<4;++r)
    t[ly+8*r][lx] = src[(size_t)(by*32+ly+8*r)*1024 + bx*32+lx];
  __syncthreads();
  #pragma unroll
  for(int r=0;r<4;++r)
    dst[(size_t)(bx*32+ly+8*r)*1024 + by*32+lx] = f2bf(t[lx][ly+8*r]);
}

// all small setup packs in one launch (grid 260 blocks x 256)
// blk 0..255: bias_comp rows -> bc; blk 256: b768; blk 257: b1024; blk 258-259: rw1t
__global__ __launch_bounds__(256) void small_pack(
    const float* __restrict__ spo_w, const float* __restrict__ spv_b, const float* __restrict__ spo_b,
    const float* __restrict__ de_b1, const float* __restrict__ hf_b1, const float* __restrict__ lt_b1,
    const float* __restrict__ sim_b1, const float* __restrict__ rout_b1,
    const float* __restrict__ rout_w1,
    float* __restrict__ bc, float* __restrict__ b768, float* __restrict__ b1024,
    float* __restrict__ rw1t)
{
  const int b=blockIdx.x, tid=threadIdx.x;
  if(b<256){
    const int wv=tid>>6, lane=tid&63;
    const int rowi=b*4+wv;
    float s=0.f;
    const float* wr=spo_w+(size_t)rowi*1024;
    #pragma unroll
    for(int j=0;j<16;++j) s+=wr[j*64+lane]*spv_b[j*64+lane];
    s=wred(s);
    if(lane==0) bc[rowi]=spo_b[rowi]+s;
  } else if(b==256){
    for(int i=tid;i<768;i+=256){
      float v = (i<256)? de_b1[i] : (i<512? hf_b1[i-256] : lt_b1[i-512]);
      b768[i]=v;
    }
  } else if(b==257){
    for(int i=tid;i<1024;i+=256) b1024[i]= (i<512)? sim_b1[i] : rout_b1[i-512];
  } else {
    int base=(b-258)*1536;
    for(int t=tid;t<1536;t+=256){
      int i=base+t;
      if(i<3072){
        int e=i>>9, col=i&511;
        rw1t[i]=rout_w1[(size_t)col*1030+1024+e];
      }
    }
  }
}

// ---------------- GEMM: fused epilogues, global_load_lds staging, XCD swizzle ----------
// EPI 0: C bf16 = v    1: C f32 = v    2: C bf16 = v*bf2f(auxb)   (spo: att*x_hi)
//     3: comb(bf16)  = w[0]*v
//     4: comb(bf16) += w[1]*(v + bf2f(auxb)*auxf)   (gate bf16, x f32)
//     5: comb(bf16) += w[3]*(x0 + (v-x0)*x0), x0=bf2f(auxb)
//     6: comb(bf16) += w[5]*sgn(x0)*sqrt(|v*x0|+1e-8), x0=bf2f(auxb)
//     7: C f32 = v + auxf (residual)
template<int ACT, int EPI>
__global__ __launch_bounds__(256) void gemm_bt(
    const u16* __restrict__ A, const u16* __restrict__ W,
    const float* __restrict__ bias, const u16* __restrict__ auxb,
    const float* __restrict__ auxf, const float* __restrict__ wsel,
    u16* __restrict__ comb, void* __restrict__ Cv, int M, int N, int K, int lda)
{
  __shared__ __align__(16) u16 lA[128*64];
  __shared__ __align__(16) u16 lB[128*64];
  const int tid=threadIdx.x, lane=tid&63, wv=tid>>6;
  const int wr=wv>>1, wc=wv&1;
  const int gx=gridDim.x;
  const int nwg=gx*gridDim.y;
  const int flat=blockIdx.y*gx+blockIdx.x;
  const int chunk=nwg>>3;
  const int nf=(flat&7)*chunk + (flat>>3);
  const int bn=(nf%gx)*128, bm=(nf/gx)*128;
  f32x4 acc[4][4];
  #pragma unroll
  for(int m=0;m<4;++m){
    #pragma unroll
    for(int n=0;n<4;++n) acc[m][n]=(f32x4)0.f;
  }
  const int srow = wv*8 + (lane>>3);
  const int scol = (lane&7)*8;
  for(int kt=0;kt<K;kt+=64){
    #pragma unroll
    for(int i=0;i<4;++i){
      gload16(A + (size_t)(bm + i*32 + srow)*lda + kt + scol, &lA[(i*32 + wv*8)*64]);
      gload16(W + (size_t)(bn + i*32 + srow)*K + kt + scol, &lB[(i*32 + wv*8)*64]);
    }
    __syncthreads();
    #pragma unroll
    for(int kk=0;kk<2;++kk){
      const int fr=lane&15, kc=kk*32+(lane>>4)*8;
      short8 af[4], bfr[4];
      #pragma unroll
      for(int m=0;m<4;++m) af[m]=*(const short8*)&lA[(wr*64+m*16+fr)*64+kc];
      #pragma unroll
      for(int n=0;n<4;++n) bfr[n]=*(const short8*)&lB[(wc*64+n*16+fr)*64+kc];
      #pragma unroll
      for(int m=0;m<4;++m){
        #pragma unroll
        for(int n=0;n<4;++n)
          acc[m][n]=__builtin_amdgcn_mfma_f32_16x16x32_bf16(af[m],bfr[n],acc[m][n],0,0,0);
      }
    }
    __syncthreads();
  }
  const int fr=lane&15, fq=lane>>4;
  #pragma unroll
  for(int m=0;m<4;++m){
    #pragma unroll
    for(int n=0;n<4;++n){
      const int col = bn + wc*64 + n*16 + fr;
      const float bv = bias ? bias[col] : 0.f;
      #pragma unroll
      for(int j=0;j<4;++j){
        const int row = bm + wr*64 + m*16 + fq*4 + j;
        const size_t idx = (size_t)row*N+col;
        float v = acc[m][n][j] + bv;
        if(ACT==5){
          v = (col<256) ? fmaxf(v,0.f) : (col<512 ? tanhf(v) : (v>0.f?v:(__expf(v)-1.f)));
        } else v = actf(ACT, v);
        if(EPI==0){ ((u16*)Cv)[idx]=f2bf(v); }
        else if(EPI==1){ ((float*)Cv)[idx]=v; }
        else if(EPI==2){ ((u16*)Cv)[idx]=f2bf(v*bf2f(auxb[idx])); }
        else if(EPI==3){ comb[idx]=f2bf(wsel[row*6+0]*v); }
        else if(EPI==4){ comb[idx]=f2bf(bf2f(comb[idx])+wsel[row*6+1]*(v + bf2f(auxb[idx])*auxf[idx])); }
        else if(EPI==5){ float x0=bf2f(auxb[idx]); comb[idx]=f2bf(bf2f(comb[idx])+wsel[row*6+3]*(x0+(v-x0)*x0)); }
        else if(EPI==6){
          float x0=bf2f(auxb[idx]);
          float sg=(x0>0.f)?1.f:((x0<0.f)?-1.f:0.f);
          comb[idx]=f2bf(bf2f(comb[idx])+wsel[row*6+5]*sg*sqrtf(fabsf(v*x0)+1e-8f));
        }
        else { ((float*)Cv)[idx]=v+auxf[idx]; }
      }
    }
  }
}

// ---------------- merged split-precision GEMM (3-term), 128x128 tile, XCD swizzle ------
__global__ __launch_bounds__(256) void gemm_split2(
    const u16* __restrict__ Ah, const u16* __restrict__ Al,
    const u16* __restrict__ Wh, const u16* __restrict__ Wl,
    const float* __restrict__ bias, float* __restrict__ C, int M, int N, int K)
{
  const int LDL=40;
  __shared__ __align__(16) u16 lAh[128*40], lAl[128*40], lBh[128*40], lBl[128*40];
  const int tid=threadIdx.x, lane=tid&63, wv=tid>>6;
  const int wr=wv>>1, wc=wv&1;
  const int nwg=gridDim.x;
  const int wg=(blockIdx.x%8)*(nwg/8)+blockIdx.x/8;
  const int bx=wg&7, by=wg>>3;
  const int bn=bx*128, bm=by*128;
  f32x4 acc[4][4];
  #pragma unroll
  for(int m=0;m<4;++m){
    #pragma unroll
    for(int n=0;n<4;++n) acc[m][n]=(f32x4)0.f;
  }
  const int srow=tid>>2, scol=(tid&3)*8;
  for(int kt=0;kt<K;kt+=32){
    short8 rah[2],ral[2],rbh[2],rbl[2];
    #pragma unroll
    for(int i=0;i<2;++i){
      size_t ao=(size_t)(bm+i*64+srow)*K+kt+scol;
      size_t bo=(size_t)(bn+i*64+srow)*K+kt+scol;
      rah[i]=*(const short8*)(Ah+ao); ral[i]=*(const short8*)(Al+ao);
      rbh[i]=*(const short8*)(Wh+bo); rbl[i]=*(const short8*)(Wl+bo);
    }
    __syncthreads();
    #pragma unroll
    for(int i=0;i<2;++i){
      int d=(i*64+srow)*LDL+scol;
      *(short8*)&lAh[d]=rah[i]; *(short8*)&lAl[d]=ral[i];
      *(short8*)&lBh[d]=rbh[i]; *(short8*)&lBl[d]=rbl[i];
    }
    __syncthreads();
    const int fr=lane&15, kc=(lane>>4)*8;
    short8 ah[4],al[4],bh[4],bl[4];
    #pragma unroll
    for(int m=0;m<4;++m){ int r=(wr*64+m*16+fr)*LDL+kc; ah[m]=*(const short8*)&lAh[r]; al[m]=*(const short8*)&lAl[r]; }
    #pragma unroll
    for(int n=0;n<4;++n){ int r=(wc*64+n*16+fr)*LDL+kc; bh[n]=*(const short8*)&lBh[r]; bl[n]=*(const short8*)&lBl[r]; }
    #pragma unroll
    for(int m=0;m<4;++m){
      #pragma unroll
      for(int n=0;n<4;++n){
        acc[m][n]=__builtin_amdgcn_mfma_f32_16x16x32_bf16(ah[m],bh[n],acc[m][n],0,0,0);
        acc[m][n]=__builtin_amdgcn_mfma_f32_16x16x32_bf16(ah[m],bl[n],acc[m][n],0,0,0);
        acc[m][n]=__builtin_amdgcn_mfma_f32_16x16x32_bf16(al[m],bh[n],acc[m][n],0,0,0);
      }
    }
  }
  const int fr=lane&15, fq=lane>>4;
  #pragma unroll
  for(int m=0;m<4;++m){
    #pragma unroll
    for(int n=0;n<4;++n){
      const int col = bn + wc*64 + n*16 + fr;
      const float bv = bias[col];
      #pragma unroll
      for(int j=0;j<4;++j){
        const int row = bm + wr*64 + m*16 + fq*4 + j;
        float v = acc[m][n][j] + bv;
        if(col<512) v=fmaxf(v,0.f);
        C[(size_t)row*N+col] = v;
      }
    }
  }
}

// ---------------- feats + x split: one wave/row, barrier-free; also emits x_hi/x_lo ----
__global__ __launch_bounds__(256) void feats_kernel(const float* __restrict__ x,
    const float* __restrict__ kw1, const float* __restrict__ kb1,
    const float* __restrict__ kw2, const float* __restrict__ kb2,
    float* __restrict__ kvals, u16* __restrict__ x_hi, u16* __restrict__ x_lo)
{
  const int lane=threadIdx.x&63, wv=threadIdx.x>>6;
  const int row=blockIdx.x*4+wv;
  const float* xr=x+(size_t)row*1024;
  u16x4* hio=(u16x4*)(x_hi+(size_t)row*1024);
  u16x4* loo=(u16x4*)(x_lo+(size_t)row*1024);
  float xv[16]; unsigned int cd[16];
  float s=0.f, ss=0.f, sa=0.f, nz=0.f, amax=0.f;
  #pragma unroll
  for(int t=0;t<4;++t){
    f32x4 v=((const f32x4*)xr)[t*64+lane];
    u16x4 h,l;
    #pragma unroll
    for(int j=0;j<4;++j){
      float f=v[j];
      union{float f;unsigned int i;} c; c.f=f;
      xv[t*4+j]=f; cd[t*4+j]=c.i&0x7fffffffu;
      h[j]=f2bf(f); l[j]=f2bf(f-bf2f(h[j]));
      s+=f; ss+=f*f; float a=fabsf(f); sa+=a; amax=fmaxf(amax,a); if(f==0.f) nz+=1.f;
    }
    hio[t*64+lane]=h; loo[t*64+lane]=l;
  }
  s=wred(s); ss=wred(ss); sa=wred(sa); nz=wred(nz); amax=wredmax(amax);
  const float mean=s/1024.f;
  const float var=(ss - s*mean)/1023.f;
  const float inv=1.f/sqrtf(var+1e-8f);
  float sk=0.f;
  #pragma unroll
  for(int j=0;j<16;++j){ float z=(xv[j]-mean)*inv; sk+=z*z*z; }
  sk=wred(sk);
  unsigned int lo=0u, hi=0x7f800000u;
  while(hi-lo>1u){
    unsigned int mid=(lo+hi)>>1;
    int c=0;
    #pragma unroll
    for(int j=0;j<16;++j) c += (cd[j] >= mid);
    c=wredi(c);
    if(c>=204) lo=mid; else hi=mid;
  }
  const unsigned int T=lo;
  float sg=0.f, cg=0.f;
  #pragma unroll
  for(int j=0;j<16;++j){ if(cd[j] > T){ sg+=fabsf(xv[j]); cg+=1.f; } }
  sg=wred(sg); cg=wred(cg);
  if(lane==0){
    union{unsigned int i;float f;} tv; tv.i=T;
    float conc=(sg + (204.f-cg)*tv.f)/(sa + 1e-8f);
    float feats[6]={ nz/1024.f, var, amax, sqrtf(ss), sk/1024.f, conc };
    float out=kb2[0];
    #pragma unroll
    for(int i=0;i<16;++i){
      float hv=kb1[i];
      #pragma unroll
      for(int j=0;j<6;++j) hv+=kw1[i*6+j]*feats[j];
      hv=fmaxf(hv,0.f);
      out+=kw2[i]*hv;
    }
    kvals[row]=1.f + 3.f*(1.f/(1.f+__expf(-out)));
  }
}

// ---------------- exact median of 8192 -> k (radix select x2, per-wave hist) -----------
__global__ __launch_bounds__(256) void median_kernel(const float* __restrict__ kvals, int* __restrict__ kint){
  __shared__ unsigned int v[8192];
  __shared__ int hist4[4*257];
  __shared__ unsigned int selT;
  __shared__ int selR;
  const int tid=threadIdx.x, lane=tid&63, wv=tid>>6;
  for(int i=tid;i<8192;i+=256){ union{float f;unsigned int u;} c; c.f=kvals[i]; v[i]=c.u; }
  __syncthreads();
  unsigned int res[2];
  for(int t=0;t<2;++t){
    int r = 8192 - (4096+t) + 1;
    unsigned int prefix=0u;
    for(int lvl=0;lvl<4;++lvl){
      const int shift=24-lvl*8;
      const unsigned int pmask = (lvl==0)?0u:(0xFFFFFFFFu<<(shift+8));
      for(int i=tid;i<4*257;i+=256) hist4[i]=0;
      __syncthreads();
      for(int i=tid;i<8192;i+=256){
        unsigned int c=v[i];
        if((c&pmask)==prefix) atomicAdd(&hist4[wv*257+((c>>shift)&0xFFu)],1);
      }
      __syncthreads();
      if(wv==0){
        int h[4]; int ls=0;
        #pragma unroll
        for(int b=0;b<4;++b){
          int bin=lane*4+b;
          h[b]=hist4[bin]+hist4[257+bin]+hist4[514+bin]+hist4[771+bin];
          ls+=h[b];
        }
        int pfx=ls;
        #pragma unroll
        for(int off=1;off<64;off<<=1){ int tt=__shfl_up(pfx,off); if(lane>=off) pfx+=tt; }
        int total=__shfl(pfx,63);
        int cgt = total - pfx;
        #pragma unroll
        for(int b=3;b>=0;--b){
          if(cgt < r && r <= cgt + h[b]){
            selT = prefix | ((unsigned int)(lane*4+b)<<shift);
            selR = r - cgt;
          }
          cgt += h[b];
        }
      }
      __syncthreads();
      prefix=selT; r=selR;
      __syncthreads();
    }
    res[t]=prefix;
  }
  if(tid==0){
    union{unsigned int u; float f;} a,b; a.u=res[0]; b.u=res[1];
    float med=0.5f*(a.f+b.f);
    int k=(int)floorf(med);
    k = k<1?1:(k>4?4:k);
    *kint=k;
  }
}

// ---------------- fused router: spec -> h-tail fix -> probs -> top-k gates -> wsel -----
// rw1t: transposed rout_w1 tail [6][512] (coalesced reads)
__global__ __launch_bounds__(256) void router_kernel(const float* __restrict__ x,
    const float* __restrict__ h, const float* __restrict__ esp,
    const float* __restrict__ w2s, const float* __restrict__ b2s,
    const float* __restrict__ rw1t, const float* __restrict__ w2r,
    const float* __restrict__ b2r, const int* __restrict__ kint,
    float* __restrict__ wsel)
{
  const int wv=threadIdx.x>>6, lane=threadIdx.x&63;
  const int row=blockIdx.x*4+wv;
  const float* xr=x+(size_t)row*1024;
  const float* hr=h+(size_t)row*1024;
  float xv[16], h0[8], h1[8];
  #pragma unroll
  for(int j=0;j<16;++j) xv[j]=xr[j*64+lane];
  #pragma unroll
  for(int j=0;j<8;++j){ h0[j]=hr[j*64+lane]; h1[j]=hr[512+j*64+lane]; }
  // spec (all lanes get result via butterfly wred)
  float spec[6];
  #pragma unroll
  for(int e=0;e<6;++e){
    float s=0.f;
    #pragma unroll
    for(int j=0;j<16;++j) s+=xv[j]*esp[e*1024+j*64+lane];
    #pragma unroll
    for(int j=0;j<8;++j) s+=h0[j]*w2s[e*512+j*64+lane];
    s=wred(s);
    spec[e]=1.f/(1.f+__expf(-(s+b2s[e])));
  }
  // fix rout hidden tail + relu (in registers, coalesced rw1t reads)
  #pragma unroll
  for(int e=0;e<6;++e){
    const float se=spec[e];
    #pragma unroll
    for(int j=0;j<8;++j) h1[j]+=se*rw1t[e*512+j*64+lane];
  }
  #pragma unroll
  for(int j=0;j<8;++j) h1[j]=fmaxf(h1[j],0.f);
  // logits + softmax
  float p[6];
  float m=-1e30f;
  #pragma unroll
  for(int e=0;e<6;++e){
    float s=0.f;
    #pragma unroll
    for(int j=0;j<8;++j) s+=h1[j]*w2r[e*512+j*64+lane];
    p[e]=wred(s)+b2r[e];
    m=fmaxf(m,p[e]);
  }
  float den=0.f;
  #pragma unroll
  for(int e=0;e<6;++e){ p[e]=__expf(p[e]-m); den+=p[e]; }
  float invd=1.f/den;
  #pragma unroll
  for(int e=0;e<6;++e) p[e]*=invd;
  if(lane==0){
    const int k=*kint;
    float w[6]={0,0,0,0,0,0};
    bool used[6]={false,false,false,false,false,false};
    int idx[4]; float val[4];
    #pragma unroll
    for(int j=0;j<4;++j){
      int bi=0; float bv=-1e30f;
      #pragma unroll
      for(int e=0;e<6;++e) if(!used[e] && p[e]>bv){ bv=p[e]; bi=e; }
      used[bi]=true; idx[j]=bi; val[j]=bv;
    }
    float mm=val[0], dd=0.f, g[4]={0,0,0,0};
    for(int j=0;j<k;++j){ g[j]=__expf(val[j]-mm); dd+=g[j]; }
    for(int j=0;j<k;++j) w[idx[j]]=g[j]/dd;
    float* o=&wsel[(size_t)row*6];
    o[0]=w[0]; o[1]=w[1]; o[2]=w[2]; o[3]=w[3]; o[4]=w[4]; o[5]=w[5];
  }
}

// ---------------- CrossField expert: MFMA, 1 wave/row, 4 rows/block, bf16 comb ---------
__global__ __launch_bounds__(256) void cf_kernel(const float* __restrict__ x,
    const float* __restrict__ w_in, const float* __restrict__ b_in,
    const float* __restrict__ w_o, const float* __restrict__ b_o,
    const float* __restrict__ w_f, const float* __restrict__ b_f,
    const float* __restrict__ wsel, u16* __restrict__ comb){
  __shared__ __align__(16) u16 smem[6400 + 4*6144];
  const int tid=threadIdx.x, wv=tid>>6, lane=tid&63;
  const int fr=lane&15, fq=lane>>4;
  for(int i=tid;i<5120;i+=256){
    float v=(i<3072)? w_in[i] : (i<4096? w_o[i-3072] : w_f[i-4096]);
    smem[(i>>5)*40 + (i&31)] = f2bf(v);
  }
  u16* wb   = smem + 6400 + wv*6144;
  float* xfl= (float*)wb;
  u16* bufA = wb + 2304;
  u16* bufB = bufA + 1280;
  u16* bufC = bufB + 1280;
  const int row = blockIdx.x*4 + wv;
  const float* xr = x + (size_t)row*1024;
  #pragma unroll
  for(int t=0;t<4;++t){
    f32x4 v = ((const f32x4*)xr)[t*64+lane];
    int e=(t*64+lane)*4;
    *(f32x4*)&xfl[(e>>5)*36 + (e&31)] = v;
  }
  __syncthreads();
  short8 xa[2];
  #pragma unroll
  for(int ft=0;ft<2;++ft){
    f32x4 a=*(const f32x4*)&xfl[(ft*16+fr)*36 + fq*8];
    f32x4 b=*(const f32x4*)&xfl[(ft*16+fr)*36 + fq*8 + 4];
    short8 s;
    s[0]=(short)f2bf(a[0]); s[1]=(short)f2bf(a[1]); s[2]=(short)f2bf(a[2]); s[3]=(short)f2bf(a[3]);
    s[4]=(short)f2bf(b[0]); s[5]=(short)f2bf(b[1]); s[6]=(short)f2bf(b[2]); s[7]=(short)f2bf(b[3]);
    xa[ft]=s;
  }
  f32x4 acc1[2][6];
  #pragma unroll
  for(int ct=0;ct<6;++ct){
    short8 wfrag=*(const short8*)&smem[(ct*16+fr)*40 + fq*8];
    #pragma unroll
    for(int ft=0;ft<2;++ft)
      acc1[ft][ct]=__builtin_amdgcn_mfma_f32_16x16x32_bf16(xa[ft],wfrag,(f32x4)0.f,0,0,0);
  }
  float bi[6];
  #pragma unroll
  for(int ct=0;ct<6;++ct) bi[ct]=b_in[ct*16+fr];
  #pragma unroll
  for(int ct=0;ct<6;++ct){
    #pragma unroll
    for(int ft=0;ft<2;++ft){
      #pragma unroll
      for(int j=0;j<4;++j){
        u16 h=f2bf(acc1[ft][ct][j]+bi[ct]);
        int rg=ft*16+fq*4+j, cg=ct*16+fr;
        if(cg<32)      bufA[rg*40+cg]=h;
        else if(cg<64) bufB[rg*40+(cg-32)]=h;
        else           bufC[(cg-64)*40+rg]=h;
      }
    }
  }
  __syncthreads();
  short8 qa0=*(const short8*)&bufA[fr*40+fq*8];
  short8 qa1=*(const short8*)&bufA[(16+fr)*40+fq*8];
  short8 kb0=*(const short8*)&bufB[fr*40+fq*8];
  short8 kb1=*(const short8*)&bufB[(16+fr)*40+fq*8];
  f32x4 aS[2][2];
  aS[0][0]=__builtin_amdgcn_mfma_f32_16x16x32_bf16(qa0,kb0,(f32x4)0.f,0,0,0);
  aS[0][1]=__builtin_amdgcn_mfma_f32_16x16x32_bf16(qa0,kb1,(f32x4)0.f,0,0,0);
  aS[1][0]=__builtin_amdgcn_mfma_f32_16x16x32_bf16(qa1,kb0,(f32x4)0.f,0,0,0);
  aS[1][1]=__builtin_amdgcn_mfma_f32_16x16x32_bf16(qa1,kb1,(f32x4)0.f,0,0,0);
  const float scale=0.17677669529663687f;
  #pragma unroll
  for(int rt=0;rt<2;++rt){
    #pragma unroll
    for(int j=0;j<4;++j){
      float e0=aS[rt][0][j]*scale, e1=aS[rt][1][j]*scale;
      float m=fmaxf(e0,e1);
      #pragma unroll
      for(int o=1;o<16;o<<=1) m=fmaxf(m,__shfl_xor(m,o));
      e0=__expf(e0-m); e1=__expf(e1-m);
      float den=e0+e1;
      #pragma unroll
      for(int o=1;o<16;o<<=1) den+=__shfl_xor(den,o);
      float inv=1.f/den;
      bufA[(rt*16+fq*4+j)*40 + fr]      = f2bf(e0*inv);
      bufA[(rt*16+fq*4+j)*40 + 16+fr]   = f2bf(e1*inv);
    }
  }
  __syncthreads();
  short8 pa0=*(const short8*)&bufA[fr*40+fq*8];
  short8 pa1=*(const short8*)&bufA[(16+fr)*40+fq*8];
  short8 vb0=*(const short8*)&bufC[fr*40+fq*8];
  short8 vb1=*(const short8*)&bufC[(16+fr)*40+fq*8];
  f32x4 aA[2][2];
  aA[0][0]=__builtin_amdgcn_mfma_f32_16x16x32_bf16(pa0,vb0,(f32x4)0.f,0,0,0);
  aA[0][1]=__builtin_amdgcn_mfma_f32_16x16x32_bf16(pa0,vb1,(f32x4)0.f,0,0,0);
  aA[1][0]=__builtin_amdgcn_mfma_f32_16x16x32_bf16(pa1,vb0,(f32x4)0.f,0,0,0);
  aA[1][1]=__builtin_amdgcn_mfma_f32_16x16x32_bf16(pa1,vb1,(f32x4)0.f,0,0,0);
  #pragma unroll
  for(int rt=0;rt<2;++rt)
    #pragma unroll
    for(int dt=0;dt<2;++dt)
      #pragma unroll
      for(int j=0;j<4;++j)
        bufB[(rt*16+fq*4+j)*40 + dt*16+fr]=f2bf(aA[rt][dt][j]);
  __syncthreads();
  short8 aa0=*(const short8*)&bufB[fr*40+fq*8];
  short8 aa1=*(const short8*)&bufB[(16+fr)*40+fq*8];
  short8 ob0=*(const short8*)&smem[(96+fr)*40+fq*8];
  short8 ob1=*(const short8*)&smem[(112+fr)*40+fq*8];
  f32x4 aF[2][2];
  aF[0][0]=__builtin_amdgcn_mfma_f32_16x16x32_bf16(aa0,ob0,(f32x4)0.f,0,0,0);
  aF[0][1]=__builtin_amdgcn_mfma_f32_16x16x32_bf16(aa0,ob1,(f32x4)0.f,0,0,0);
  aF[1][0]=__builtin_amdgcn_mfma_f32_16x16x32_bf16(aa1,ob0,(f32x4)0.f,0,0,0);
  aF[1][1]=__builtin_amdgcn_mfma_f32_16x16x32_bf16(aa1,ob1,(f32x4)0.f,0,0,0);
  float bo[2]={b_o[fr], b_o[16+fr]};
  #pragma unroll
  for(int rt=0;rt<2;++rt){
    #pragma unroll
    for(int dt=0;dt<2;++dt){
      #pragma unroll
      for(int j=0;j<4;++j){
        int fld=rt*16+fq*4+j, d=dt*16+fr;
        float attf=aF[rt][dt][j]+bo[dt];
        bufC[fld*40+d]=f2bf(attf*xfl[fld*36+d]);
      }
    }
  }
  __syncthreads();
  short8 pr0=*(const short8*)&bufC[fr*40+fq*8];
  short8 pr1=*(const short8*)&bufC[(16+fr)*40+fq*8];
  short8 fb0=*(const short8*)&smem[(128+fr)*40+fq*8];
  short8 fb1=*(const short8*)&smem[(144+fr)*40+fq*8];
  f32x4 aE[2][2];
  aE[0][0]=__builtin_amdgcn_mfma_f32_16x16x32_bf16(pr0,fb0,(f32x4)0.f,0,0,0);
  aE[0][1]=__builtin_amdgcn_mfma_f32_16x16x32_bf16(pr0,fb1,(f32x4)0.f,0,0,0);
  aE[1][0]=__builtin_amdgcn_mfma_f32_16x16x32_bf16(pr1,fb0,(f32x4)0.f,0,0,0);
  aE[1][1]=__builtin_amdgcn_mfma_f32_16x16x32_bf16(pr1,fb1,(f32x4)0.f,0,0,0);
  float bff[2]={b_f[fr], b_f[16+fr]};
  const float w2=wsel[row*6+2];
  u16* cb=&comb[(size_t)row*1024];
  #pragma unroll
  for(int rt=0;rt<2;++rt){
    #pragma unroll
    for(int dt=0;dt<2;++dt){
      #pragma unroll
      for(int j=0;j<4;++j){
        int fld=rt*16+fq*4+j, d=dt*16+fr;
        u16 old=cb[fld*32+d];
        cb[fld*32+d]=f2bf(bf2f(old)+w2*(aE[rt][dt][j]+bff[dt]));
      }
    }
  }
}

// ---------------- Temporal expert + final bf16 conversion (bf16 comb) -------------------
__global__ __launch_bounds__(256) void tp_kernel(const float* __restrict__ x,
    const float* __restrict__ wsel, const u16* __restrict__ comb,
    const float* __restrict__ tcw, const float* __restrict__ tcb,
    const float* __restrict__ tfw, const float* __restrict__ tfb,
    u16* __restrict__ obf){
  __shared__ float xs[1026];
  const int row=blockIdx.x, tid=threadIdx.x;
  f32x4 u=((const f32x4*)(x+(size_t)row*1024))[tid];
  #pragma unroll
  for(int j=0;j<4;++j) xs[1+4*tid+j]=u[j];
  if(tid==0){ xs[0]=0.f; xs[1025]=0.f; }
  __syncthreads();
  const float w4=wsel[row*6+4];
  float tc[4][3], tb[4], tf[4];
  #pragma unroll
  for(int o=0;o<4;++o){
    #pragma unroll
    for(int kh=0;kh<3;++kh) tc[o][kh]=tcw[o*3+kh];
    tb[o]=tcb[o]; tf[o]=tfw[o];
  }
  const float tfb0=tfb[0];
  u16x4 cv=((const u16x4*)(comb+(size_t)row*1024))[tid];
  u16x4 ov;
  #pragma unroll
  for(int j=0;j<4;++j){
    const int d=4*tid+j;
    float pre=tfb0;
    #pragma unroll
    for(int o=0;o<4;++o){
      float c=tb[o]+tc[o][0]*xs[d]+tc[o][1]*xs[d+1]+tc[o][2]*xs[d+2];
      pre+=tf[o]*fmaxf(c,0.f);
    }
    float wt=1.f/(1.f+__expf(-pre));
    float xv=xs[1+d];
    ov[j]=f2bf(bf2f(cv[j])+w4*xv*xv*wt);
  }
  ((u16x4*)(obf+(size_t)row*1024))[tid]=ov;
}

// =======================================================================================
extern "C" void kernel_launch(void* const* d_in, const int* in_sizes, int n_in,
                              void* d_out, int out_size, void* d_ws, size_t ws_size,
                              hipStream_t stream)
{
  const float* x     =(const float*)d_in[0];
  const float* esp   =(const float*)d_in[1];
  const float* sim_w1=(const float*)d_in[2],  *sim_b1=(const float*)d_in[3];
  const float* sim_w2=(const float*)d_in[4],  *sim_b2=(const float*)d_in[5];
  const float* rout_w1=(const float*)d_in[6], *rout_b1=(const float*)d_in[7];
  const float* rout_w2=(const float*)d_in[8], *rout_b2=(const float*)d_in[9];
  const float* kw1=(const float*)d_in[10], *kb1=(const float*)d_in[11];
  const float* kw2=(const float*)d_in[12], *kb2=(const float*)d_in[13];
  const float* spv_w=(const float*)d_in[14], *spv_b=(const float*)d_in[15];
  const float* spo_w=(const float*)d_in[16], *spo_b=(const float*)d_in[17];
  const float* spq1_w=(const float*)d_in[18], *spq1_b=(const float*)d_in[19];
  const float* spq2_w=(const float*)d_in[20], *spq2_b=(const float*)d_in[21];
  const float* de_w1=(const float*)d_in[22], *de_b1=(const float*)d_in[23];
  const float* de_w2=(const float*)d_in[24], *de_b2=(const float*)d_in[25];
  const float* de_gw=(const float*)d_in[26], *de_gb=(const float*)d_in[27];
  const float* cf_inw=(const float*)d_in[28], *cf_inb=(const float*)d_in[29];
  const float* cf_ow=(const float*)d_in[30], *cf_ob=(const float*)d_in[31];
  const float* cf_fw=(const float*)d_in[32], *cf_fb=(const float*)d_in[33];
  const float* hf_w1=(const float*)d_in[34], *hf_b1=(const float*)d_in[35];
  const float* hf_w2=(const float*)d_in[36], *hf_b2=(const float*)d_in[37];
  const float* tc_w=(const float*)d_in[38], *tc_b=(const float*)d_in[39];
  const float* tf_w=(const float*)d_in[40], *tf_b=(const float*)d_in[41];
  const float* lt_w1=(const float*)d_in[42], *lt_b1=(const float*)d_in[43];
  const float* lt_w2=(const float*)d_in[44], *lt_b2=(const float*)d_in[45];
  const float* op_w=(const float*)d_in[46], *op_b=(const float*)d_in[47];
  float* out=(float*)d_out;
  (void)in_sizes; (void)n_in; (void)out_size; (void)ws_size;

  constexpr int NB=8192;
  const size_t BD=(size_t)NB*1024;
  char* base=(char*)d_ws; size_t off=0;
  auto carve=[&](size_t n)->void*{ void* q=base+off; off+=(n+255)&~(size_t)255; return q; };
  u16*  comb =(u16*)carve(BD*2);
  u16*  bufA =(u16*)carve(BD*2);
  u16*  bufB =(u16*)carve(BD*2);
  u16*  x_hi =(u16*)carve(BD*2);
  u16*  x_lo =(u16*)carve(BD*2);
  float* h1024=(float*)carve(BD*4);
  u16*  h768 =(u16*)carve((size_t)NB*768*2);
  u16* w1024h=(u16*)carve((size_t)1024*1024*2);
  u16* w1024l=(u16*)carve((size_t)1024*1024*2);
  u16* spv_bf =(u16*)carve((size_t)1024*1024*2);
  u16* spo_bf =(u16*)carve((size_t)1024*1024*2);
  u16* spq1_bf=(u16*)carve((size_t)1024*1024*2);
  u16* spq2_bf=(u16*)carve((size_t)1024*1024*2);
  u16* w768_bf=(u16*)carve((size_t)768*1024*2);
  u16* dew2_bf=(u16*)carve((size_t)1024*256*2);
  u16* degw_bf=(u16*)carve((size_t)1024*1024*2);
  u16* hfw2_bf=(u16*)carve((size_t)1024*256*2);
  u16* ltw2_bf=(u16*)carve((size_t)1024*256*2);
  u16* opw_bf =(u16*)carve((size_t)1024*1024*2);
  u16* spvT_bf=(u16*)carve((size_t)1024*1024*2);
  float* bc   =(float*)carve((size_t)1024*4);
  float* b768 =(float*)carve((size_t)768*4);
  float* b1024=(float*)carve((size_t)1024*4);
  float* rw1t =(float*)carve((size_t)3072*4);
  float* wsel=(float*)carve((size_t)NB*6*4);
  float* kvals=(float*)carve((size_t)NB*4);
  int*   kint=(int*)carve(256);

  const dim3 blk(256);
  auto cgrid=[&](int n4)->dim3{ int g=(n4+255)/256; return dim3(g>2048?2048:g); };

  // ---- feats + x split (x read once) ----
  feats_kernel<<<dim3(2048),blk,0,stream>>>(x, kw1,kb1,kw2,kb2, kvals, x_hi, x_lo);
  median_kernel<<<dim3(1),blk,0,stream>>>(kvals, kint);

  // ---- weight conversions (batched) ----
  cvt_split<<<cgrid(131072),blk,0,stream>>>(sim_w1, w1024h, w1024l, 131072);
  cvt_split_rw1<<<cgrid(131072),blk,0,stream>>>(rout_w1, w1024h+524288, w1024l+524288);
  cvt6_kernel<<<cgrid(6*262144),blk,0,stream>>>(spv_w,spo_w,spq1_w,spq2_w,de_gw,op_w,
                                                spv_bf,spo_bf,spq1_bf,spq2_bf,degw_bf,opw_bf, 262144);
  cvt6_kernel<<<cgrid(6*65536),blk,0,stream>>>(de_w1,de_w2,hf_w1,hf_w2,lt_w1,lt_w2,
                                               w768_bf,dew2_bf,w768_bf+262144,hfw2_bf,w768_bf+524288,ltw2_bf, 65536);
  transpose_bf<<<dim3(1024),blk,0,stream>>>(spv_w, spvT_bf);
  small_pack<<<dim3(260),blk,0,stream>>>(spo_w, spv_b, spo_b, de_b1, hf_b1, lt_b1,
                                         sim_b1, rout_b1, rout_w1, bc, b768, b1024, rw1t);

  // ---- routing pipeline (merged N=1024 split GEMM + fused router) ----
  gemm_split2<<<dim3(512),blk,0,stream>>>(x_hi,x_lo, w1024h,w1024l, b1024, h1024, NB,1024,1024);
  router_kernel<<<dim3(2048),blk,0,stream>>>(x, h1024, esp, sim_w2, sim_b2, rw1t, rout_w2, rout_b2, kint, wsel);

  // ---- compose Wc = spo_w @ spv_w (h1024 free now); att = x@Wc^T + bc ----
  gemm_bt<0,1><<<dim3(8,8),blk,0,stream>>>(spo_bf, spvT_bf, nullptr, nullptr, nullptr, nullptr, nullptr, h1024, 1024,1024,1024,1024);
  cvt_kernel<<<cgrid(262144),blk,0,stream>>>(h1024, spv_bf, 262144);

  // ---- expert 0: SparseQuadratic (3 GEMMs via composition) ----
  gemm_bt<0,2><<<dim3(8,64),blk,0,stream>>>(x_hi, spv_bf, bc, x_hi, nullptr, nullptr, nullptr, bufB, NB,1024,1024,1024);
  gemm_bt<1,0><<<dim3(8,64),blk,0,stream>>>(bufB, spq1_bf, spq1_b, nullptr, nullptr, nullptr, nullptr, bufA, NB,1024,1024,1024);
  gemm_bt<0,3><<<dim3(8,64),blk,0,stream>>>(bufA, spq2_bf, spq2_b, nullptr, nullptr, wsel, comb, nullptr, NB,1024,1024,1024);

  // ---- merged first layers: h768 = act768(x @ [de_w1;hf_w1;lt_w1]^T + b768) ----
  gemm_bt<5,0><<<dim3(6,64),blk,0,stream>>>(x_hi, w768_bf, b768, nullptr, nullptr, nullptr, nullptr, h768, NB,768,1024,1024);

  // ---- expert 1: DenseQuadratic ----
  gemm_bt<2,0><<<dim3(8,64),blk,0,stream>>>(x_hi, degw_bf, de_gb, nullptr, nullptr, nullptr, nullptr, bufB, NB,1024,1024,1024);
  gemm_bt<0,4><<<dim3(8,64),blk,0,stream>>>(h768, dew2_bf, de_b2, bufB, x, wsel, comb, nullptr, NB,1024,256,768);

  // ---- expert 2: CrossField (MFMA, fused accumulate) ----
  cf_kernel<<<dim3(2048),blk,0,stream>>>(x, cf_inw, cf_inb, cf_ow, cf_ob, cf_fw, cf_fb, wsel, comb);

  // ---- expert 3: HighFreq ----
  gemm_bt<0,5><<<dim3(8,64),blk,0,stream>>>(h768+256, hfw2_bf, hf_b2, x_hi, nullptr, wsel, comb, nullptr, NB,1024,256,768);

  // ---- expert 5: LongTail ----
  gemm_bt<0,6><<<dim3(8,64),blk,0,stream>>>(h768+512, ltw2_bf, lt_b2, x_hi, nullptr, wsel, comb, nullptr, NB,1024,256,768);

  // ---- expert 4: Temporal (last comb reader) + final bf16 conversion ----
  tp_kernel<<<dim3(NB),blk,0,stream>>>(x, wsel, comb, tc_w, tc_b, tf_w, tf_b, bufB);

  // ---- output projection + residual (f32 out) ----
  gemm_bt<0,7><<<dim3(8,64),blk,0,stream>>>(bufB, opw_bf, op_b, nullptr, x, nullptr, nullptr, out, NB,1024,1024,1024);
}

// Round 22
// 541.982 us; speedup vs baseline: 1.0568x; 1.0235x over previous
//
#include <hip/hip_runtime.h>
#include <stdint.h>

typedef unsigned short u16;
typedef __attribute__((ext_vector_type(2))) float f32x2;
typedef __attribute__((ext_vector_type(4))) float f32x4;
typedef __attribute__((ext_vector_type(4))) unsigned short u16x4;
typedef __attribute__((ext_vector_type(8))) short short8;

#define DEV static __device__ __forceinline__

DEV float bf2f(u16 u){ union{unsigned int i; float f;} v; v.i=((unsigned int)u)<<16; return v.f; }
DEV u16 f2bf(float f){ union{float f; unsigned int i;} v; v.f=f; unsigned int u=v.i;
  return (u16)((u + 0x7FFFu + ((u>>16)&1u))>>16); }
DEV float wred(float v){ for(int o=32;o;o>>=1) v += __shfl_xor(v,o); return v; }
DEV float wredmax(float v){ for(int o=32;o;o>>=1) v = fmaxf(v,__shfl_xor(v,o)); return v; }
DEV int wredi(int v){ for(int o=32;o;o>>=1) v += __shfl_xor(v,o); return v; }

DEV void gload16(const void* g, void* l){
  __builtin_amdgcn_global_load_lds((const __attribute__((address_space(1))) unsigned int*)g,
                                   (__attribute__((address_space(3))) unsigned int*)l, 16, 0, 0);
}

DEV float actf(int ACT, float v){
  if(ACT==1) return v>0.f?v:0.f;
  if(ACT==2) return 1.f/(1.f+__expf(-v));
  if(ACT==3) return tanhf(v);
  if(ACT==4) return v>0.f?v:(__expf(v)-1.f);
  return v;
}

// ---------------- f32 -> bf16 conversions ----------------
__global__ void cvt5_kernel(
    const float* __restrict__ s0, const float* __restrict__ s1, const float* __restrict__ s2,
    const float* __restrict__ s3, const float* __restrict__ s4,
    u16* __restrict__ d0, u16* __restrict__ d1, u16* __restrict__ d2,
    u16* __restrict__ d3, u16* __restrict__ d4, int n4each){
  const float* ss[5]={s0,s1,s2,s3,s4};
  u16* dd[5]={d0,d1,d2,d3,d4};
  const int total=5*n4each;
  for(int i=blockIdx.x*blockDim.x+threadIdx.x; i<total; i+=gridDim.x*blockDim.x){
    int b=i/n4each, r=i-b*n4each;
    f32x4 v=((const f32x4*)ss[b])[r];
    u16x4 o;
    #pragma unroll
    for(int j=0;j<4;++j) o[j]=f2bf(v[j]);
    ((u16x4*)dd[b])[r]=o;
  }
}

__global__ void cvt6_kernel(
    const float* __restrict__ s0, const float* __restrict__ s1, const float* __restrict__ s2,
    const float* __restrict__ s3, const float* __restrict__ s4, const float* __restrict__ s5,
    u16* __restrict__ d0, u16* __restrict__ d1, u16* __restrict__ d2,
    u16* __restrict__ d3, u16* __restrict__ d4, u16* __restrict__ d5, int n4each){
  const float* ss[6]={s0,s1,s2,s3,s4,s5};
  u16* dd[6]={d0,d1,d2,d3,d4,d5};
  const int total=6*n4each;
  for(int i=blockIdx.x*blockDim.x+threadIdx.x; i<total; i+=gridDim.x*blockDim.x){
    int b=i/n4each, r=i-b*n4each;
    f32x4 v=((const f32x4*)ss[b])[r];
    u16x4 o;
    #pragma unroll
    for(int j=0;j<4;++j) o[j]=f2bf(v[j]);
    ((u16x4*)dd[b])[r]=o;
  }
}

__global__ void cvt_split(const float* __restrict__ s, u16* __restrict__ hi, u16* __restrict__ lo, int n4){
  for(int i=blockIdx.x*blockDim.x+threadIdx.x; i<n4; i+=gridDim.x*blockDim.x){
    f32x4 v=((const f32x4*)s)[i];
    u16x4 h,l;
    #pragma unroll
    for(int j=0;j<4;++j){ h[j]=f2bf(v[j]); l[j]=f2bf(v[j]-bf2f(h[j])); }
    ((u16x4*)hi)[i]=h; ((u16x4*)lo)[i]=l;
  }
}

__global__ void cvt_split_rw1(const float* __restrict__ src, u16* __restrict__ hi, u16* __restrict__ lo){
  for(int i=blockIdx.x*blockDim.x+threadIdx.x; i<512*1024; i+=gridDim.x*blockDim.x){
    int r=i>>10, c=i&1023;
    float v=src[(size_t)r*1030+c];
    u16 h=f2bf(v);
    hi[i]=h; lo[i]=f2bf(v-bf2f(h));
  }
}

// transpose 1024x1024 f32 -> bf16: dst[j][i] = bf16(src[i][j])
__global__ __launch_bounds__(256) void transpose_bf(const float* __restrict__ src, u16* __restrict__ dst){
  __shared__ float t[32][33];
  const int bx=blockIdx.x&31, by=blockIdx.x>>5;
  const int lx=threadIdx.x&31, ly=threadIdx.x>>5;
  #pragma unroll
  for(int r=0;r<4;++r)
    t[ly+8*r][lx] = src[(size_t)(by*32+ly+8*r)*1024 + bx*32+lx];
  __syncthreads();
  #pragma unroll
  for(int r=0;r<4;++r)
    dst[(size_t)(bx*32+ly+8*r)*1024 + by*32+lx] = f2bf(t[lx][ly+8*r]);
}

// all small setup packs in one launch (grid 260 blocks x 256)
__global__ __launch_bounds__(256) void small_pack(
    const float* __restrict__ spo_w, const float* __restrict__ spv_b, const float* __restrict__ spo_b,
    const float* __restrict__ de_b1, const float* __restrict__ hf_b1, const float* __restrict__ lt_b1,
    const float* __restrict__ sim_b1, const float* __restrict__ rout_b1,
    const float* __restrict__ rout_w1,
    float* __restrict__ bc, float* __restrict__ b768, float* __restrict__ b1024,
    float* __restrict__ rw1t)
{
  const int b=blockIdx.x, tid=threadIdx.x;
  if(b<256){
    const int wv=tid>>6, lane=tid&63;
    const int rowi=b*4+wv;
    float s=0.f;
    const float* wr=spo_w+(size_t)rowi*1024;
    #pragma unroll
    for(int j=0;j<16;++j) s+=wr[j*64+lane]*spv_b[j*64+lane];
    s=wred(s);
    if(lane==0) bc[rowi]=spo_b[rowi]+s;
  } else if(b==256){
    for(int i=tid;i<768;i+=256){
      float v = (i<256)? de_b1[i] : (i<512? hf_b1[i-256] : lt_b1[i-512]);
      b768[i]=v;
    }
  } else if(b==257){
    for(int i=tid;i<1024;i+=256) b1024[i]= (i<512)? sim_b1[i] : rout_b1[i-512];
  } else {
    int base=(b-258)*1536;
    for(int t=tid;t<1536;t+=256){
      int i=base+t;
      if(i<3072){
        int e=i>>9, col=i&511;
        rw1t[i]=rout_w1[(size_t)col*1030+1024+e];
      }
    }
  }
}

// ---------------- GEMM: fused epilogues, global_load_lds staging, XCD swizzle ----------
// EPI 0: C bf16 = v    1: C f32 = v    2: C bf16 = v*bf2f(auxb)   (spo: att*x_hi)
//     3: comb(bf16)  = w[0]*v
//     4: comb(bf16) += w[1]*(v + bf2f(auxb)*bf2f(auxh))   (gate bf16, x via x_hi)
//     5: comb(bf16) += w[3]*(x0 + (v-x0)*x0), x0=bf2f(auxb)
//     6: comb(bf16) += w[5]*sgn(x0)*sqrt(|v*x0|+1e-8), x0=bf2f(auxb)
//     7: C f32 = v + auxf (residual, f32 x)
template<int ACT, int EPI>
__global__ __launch_bounds__(256) void gemm_bt(
    const u16* __restrict__ A, const u16* __restrict__ W,
    const float* __restrict__ bias, const u16* __restrict__ auxb,
    const float* __restrict__ auxf, const float* __restrict__ wsel,
    u16* __restrict__ comb, void* __restrict__ Cv, const u16* __restrict__ auxh,
    int M, int N, int K, int lda)
{
  __shared__ __align__(16) u16 lA[128*64];
  __shared__ __align__(16) u16 lB[128*64];
  const int tid=threadIdx.x, lane=tid&63, wv=tid>>6;
  const int wr=wv>>1, wc=wv&1;
  const int gx=gridDim.x;
  const int nwg=gx*gridDim.y;
  const int flat=blockIdx.y*gx+blockIdx.x;
  const int chunk=nwg>>3;
  const int nf=(flat&7)*chunk + (flat>>3);
  const int bn=(nf%gx)*128, bm=(nf/gx)*128;
  f32x4 acc[4][4];
  #pragma unroll
  for(int m=0;m<4;++m){
    #pragma unroll
    for(int n=0;n<4;++n) acc[m][n]=(f32x4)0.f;
  }
  const int srow = wv*8 + (lane>>3);
  const int scol = (lane&7)*8;
  for(int kt=0;kt<K;kt+=64){
    #pragma unroll
    for(int i=0;i<4;++i){
      gload16(A + (size_t)(bm + i*32 + srow)*lda + kt + scol, &lA[(i*32 + wv*8)*64]);
      gload16(W + (size_t)(bn + i*32 + srow)*K + kt + scol, &lB[(i*32 + wv*8)*64]);
    }
    __syncthreads();
    #pragma unroll
    for(int kk=0;kk<2;++kk){
      const int fr=lane&15, kc=kk*32+(lane>>4)*8;
      short8 af[4], bfr[4];
      #pragma unroll
      for(int m=0;m<4;++m) af[m]=*(const short8*)&lA[(wr*64+m*16+fr)*64+kc];
      #pragma unroll
      for(int n=0;n<4;++n) bfr[n]=*(const short8*)&lB[(wc*64+n*16+fr)*64+kc];
      #pragma unroll
      for(int m=0;m<4;++m){
        #pragma unroll
        for(int n=0;n<4;++n)
          acc[m][n]=__builtin_amdgcn_mfma_f32_16x16x32_bf16(af[m],bfr[n],acc[m][n],0,0,0);
      }
    }
    __syncthreads();
  }
  const int fr=lane&15, fq=lane>>4;
  #pragma unroll
  for(int m=0;m<4;++m){
    #pragma unroll
    for(int n=0;n<4;++n){
      const int col = bn + wc*64 + n*16 + fr;
      const float bv = bias ? bias[col] : 0.f;
      #pragma unroll
      for(int j=0;j<4;++j){
        const int row = bm + wr*64 + m*16 + fq*4 + j;
        const size_t idx = (size_t)row*N+col;
        float v = acc[m][n][j] + bv;
        if(ACT==5){
          v = (col<256) ? fmaxf(v,0.f) : (col<512 ? tanhf(v) : (v>0.f?v:(__expf(v)-1.f)));
        } else v = actf(ACT, v);
        if(EPI==0){ ((u16*)Cv)[idx]=f2bf(v); }
        else if(EPI==1){ ((float*)Cv)[idx]=v; }
        else if(EPI==2){ ((u16*)Cv)[idx]=f2bf(v*bf2f(auxb[idx])); }
        else if(EPI==3){ comb[idx]=f2bf(wsel[row*6+0]*v); }
        else if(EPI==4){ comb[idx]=f2bf(bf2f(comb[idx])+wsel[row*6+1]*(v + bf2f(auxb[idx])*bf2f(auxh[idx]))); }
        else if(EPI==5){ float x0=bf2f(auxb[idx]); comb[idx]=f2bf(bf2f(comb[idx])+wsel[row*6+3]*(x0+(v-x0)*x0)); }
        else if(EPI==6){
          float x0=bf2f(auxb[idx]);
          float sg=(x0>0.f)?1.f:((x0<0.f)?-1.f:0.f);
          comb[idx]=f2bf(bf2f(comb[idx])+wsel[row*6+5]*sg*sqrtf(fabsf(v*x0)+1e-8f));
        }
        else { ((float*)Cv)[idx]=v+auxf[idx]; }
      }
    }
  }
}

// ---------------- merged split-precision GEMM (3-term), 128x128 tile, XCD swizzle ------
__global__ __launch_bounds__(256) void gemm_split2(
    const u16* __restrict__ Ah, const u16* __restrict__ Al,
    const u16* __restrict__ Wh, const u16* __restrict__ Wl,
    const float* __restrict__ bias, float* __restrict__ C, int M, int N, int K)
{
  const int LDL=40;
  __shared__ __align__(16) u16 lAh[128*40], lAl[128*40], lBh[128*40], lBl[128*40];
  const int tid=threadIdx.x, lane=tid&63, wv=tid>>6;
  const int wr=wv>>1, wc=wv&1;
  const int nwg=gridDim.x;
  const int wg=(blockIdx.x%8)*(nwg/8)+blockIdx.x/8;
  const int bx=wg&7, by=wg>>3;
  const int bn=bx*128, bm=by*128;
  f32x4 acc[4][4];
  #pragma unroll
  for(int m=0;m<4;++m){
    #pragma unroll
    for(int n=0;n<4;++n) acc[m][n]=(f32x4)0.f;
  }
  const int srow=tid>>2, scol=(tid&3)*8;
  for(int kt=0;kt<K;kt+=32){
    short8 rah[2],ral[2],rbh[2],rbl[2];
    #pragma unroll
    for(int i=0;i<2;++i){
      size_t ao=(size_t)(bm+i*64+srow)*K+kt+scol;
      size_t bo=(size_t)(bn+i*64+srow)*K+kt+scol;
      rah[i]=*(const short8*)(Ah+ao); ral[i]=*(const short8*)(Al+ao);
      rbh[i]=*(const short8*)(Wh+bo); rbl[i]=*(const short8*)(Wl+bo);
    }
    __syncthreads();
    #pragma unroll
    for(int i=0;i<2;++i){
      int d=(i*64+srow)*LDL+scol;
      *(short8*)&lAh[d]=rah[i]; *(short8*)&lAl[d]=ral[i];
      *(short8*)&lBh[d]=rbh[i]; *(short8*)&lBl[d]=rbl[i];
    }
    __syncthreads();
    const int fr=lane&15, kc=(lane>>4)*8;
    short8 ah[4],al[4],bh[4],bl[4];
    #pragma unroll
    for(int m=0;m<4;++m){ int r=(wr*64+m*16+fr)*LDL+kc; ah[m]=*(const short8*)&lAh[r]; al[m]=*(const short8*)&lAl[r]; }
    #pragma unroll
    for(int n=0;n<4;++n){ int r=(wc*64+n*16+fr)*LDL+kc; bh[n]=*(const short8*)&lBh[r]; bl[n]=*(const short8*)&lBl[r]; }
    #pragma unroll
    for(int m=0;m<4;++m){
      #pragma unroll
      for(int n=0;n<4;++n){
        acc[m][n]=__builtin_amdgcn_mfma_f32_16x16x32_bf16(ah[m],bh[n],acc[m][n],0,0,0);
        acc[m][n]=__builtin_amdgcn_mfma_f32_16x16x32_bf16(ah[m],bl[n],acc[m][n],0,0,0);
        acc[m][n]=__builtin_amdgcn_mfma_f32_16x16x32_bf16(al[m],bh[n],acc[m][n],0,0,0);
      }
    }
  }
  const int fr=lane&15, fq=lane>>4;
  #pragma unroll
  for(int m=0;m<4;++m){
    #pragma unroll
    for(int n=0;n<4;++n){
      const int col = bn + wc*64 + n*16 + fr;
      const float bv = bias[col];
      #pragma unroll
      for(int j=0;j<4;++j){
        const int row = bm + wr*64 + m*16 + fq*4 + j;
        float v = acc[m][n][j] + bv;
        if(col<512) v=fmaxf(v,0.f);
        C[(size_t)row*N+col] = v;
      }
    }
  }
}

// ---------------- feats + x split: one wave/row, barrier-free; also emits x_hi/x_lo ----
__global__ __launch_bounds__(256) void feats_kernel(const float* __restrict__ x,
    const float* __restrict__ kw1, const float* __restrict__ kb1,
    const float* __restrict__ kw2, const float* __restrict__ kb2,
    float* __restrict__ kvals, u16* __restrict__ x_hi, u16* __restrict__ x_lo)
{
  const int lane=threadIdx.x&63, wv=threadIdx.x>>6;
  const int row=blockIdx.x*4+wv;
  const float* xr=x+(size_t)row*1024;
  u16x4* hio=(u16x4*)(x_hi+(size_t)row*1024);
  u16x4* loo=(u16x4*)(x_lo+(size_t)row*1024);
  float xv[16]; unsigned int cd[16];
  float s=0.f, ss=0.f, sa=0.f, nz=0.f, amax=0.f;
  #pragma unroll
  for(int t=0;t<4;++t){
    f32x4 v=((const f32x4*)xr)[t*64+lane];
    u16x4 h,l;
    #pragma unroll
    for(int j=0;j<4;++j){
      float f=v[j];
      union{float f;unsigned int i;} c; c.f=f;
      xv[t*4+j]=f; cd[t*4+j]=c.i&0x7fffffffu;
      h[j]=f2bf(f); l[j]=f2bf(f-bf2f(h[j]));
      s+=f; ss+=f*f; float a=fabsf(f); sa+=a; amax=fmaxf(amax,a); if(f==0.f) nz+=1.f;
    }
    hio[t*64+lane]=h; loo[t*64+lane]=l;
  }
  s=wred(s); ss=wred(ss); sa=wred(sa); nz=wred(nz); amax=wredmax(amax);
  const float mean=s/1024.f;
  const float var=(ss - s*mean)/1023.f;
  const float inv=1.f/sqrtf(var+1e-8f);
  float sk=0.f;
  #pragma unroll
  for(int j=0;j<16;++j){ float z=(xv[j]-mean)*inv; sk+=z*z*z; }
  sk=wred(sk);
  unsigned int lo=0u, hi=0x7f800000u;
  while(hi-lo>1u){
    unsigned int mid=(lo+hi)>>1;
    int c=0;
    #pragma unroll
    for(int j=0;j<16;++j) c += (cd[j] >= mid);
    c=wredi(c);
    if(c>=204) lo=mid; else hi=mid;
  }
  const unsigned int T=lo;
  float sg=0.f, cg=0.f;
  #pragma unroll
  for(int j=0;j<16;++j){ if(cd[j] > T){ sg+=fabsf(xv[j]); cg+=1.f; } }
  sg=wred(sg); cg=wred(cg);
  if(lane==0){
    union{unsigned int i;float f;} tv; tv.i=T;
    float conc=(sg + (204.f-cg)*tv.f)/(sa + 1e-8f);
    float feats[6]={ nz/1024.f, var, amax, sqrtf(ss), sk/1024.f, conc };
    float out=kb2[0];
    #pragma unroll
    for(int i=0;i<16;++i){
      float hv=kb1[i];
      #pragma unroll
      for(int j=0;j<6;++j) hv+=kw1[i*6+j]*feats[j];
      hv=fmaxf(hv,0.f);
      out+=kw2[i]*hv;
    }
    kvals[row]=1.f + 3.f*(1.f/(1.f+__expf(-out)));
  }
}

// ---------------- exact median of 8192 -> k (radix select x2, per-wave hist) -----------
__global__ __launch_bounds__(256) void median_kernel(const float* __restrict__ kvals, int* __restrict__ kint){
  __shared__ unsigned int v[8192];
  __shared__ int hist4[4*257];
  __shared__ unsigned int selT;
  __shared__ int selR;
  const int tid=threadIdx.x, lane=tid&63, wv=tid>>6;
  for(int i=tid;i<8192;i+=256){ union{float f;unsigned int u;} c; c.f=kvals[i]; v[i]=c.u; }
  __syncthreads();
  unsigned int res[2];
  for(int t=0;t<2;++t){
    int r = 8192 - (4096+t) + 1;
    unsigned int prefix=0u;
    for(int lvl=0;lvl<4;++lvl){
      const int shift=24-lvl*8;
      const unsigned int pmask = (lvl==0)?0u:(0xFFFFFFFFu<<(shift+8));
      for(int i=tid;i<4*257;i+=256) hist4[i]=0;
      __syncthreads();
      for(int i=tid;i<8192;i+=256){
        unsigned int c=v[i];
        if((c&pmask)==prefix) atomicAdd(&hist4[wv*257+((c>>shift)&0xFFu)],1);
      }
      __syncthreads();
      if(wv==0){
        int h[4]; int ls=0;
        #pragma unroll
        for(int b=0;b<4;++b){
          int bin=lane*4+b;
          h[b]=hist4[bin]+hist4[257+bin]+hist4[514+bin]+hist4[771+bin];
          ls+=h[b];
        }
        int pfx=ls;
        #pragma unroll
        for(int off=1;off<64;off<<=1){ int tt=__shfl_up(pfx,off); if(lane>=off) pfx+=tt; }
        int total=__shfl(pfx,63);
        int cgt = total - pfx;
        #pragma unroll
        for(int b=3;b>=0;--b){
          if(cgt < r && r <= cgt + h[b]){
            selT = prefix | ((unsigned int)(lane*4+b)<<shift);
            selR = r - cgt;
          }
          cgt += h[b];
        }
      }
      __syncthreads();
      prefix=selT; r=selR;
      __syncthreads();
    }
    res[t]=prefix;
  }
  if(tid==0){
    union{unsigned int u; float f;} a,b; a.u=res[0]; b.u=res[1];
    float med=0.5f*(a.f+b.f);
    int k=(int)floorf(med);
    k = k<1?1:(k>4?4:k);
    *kint=k;
  }
}

// ---------------- fused router: spec -> h-tail fix -> probs -> top-k gates -> wsel -----
__global__ __launch_bounds__(256) void router_kernel(const float* __restrict__ x,
    const float* __restrict__ h, const float* __restrict__ esp,
    const float* __restrict__ w2s, const float* __restrict__ b2s,
    const float* __restrict__ rw1t, const float* __restrict__ w2r,
    const float* __restrict__ b2r, const int* __restrict__ kint,
    float* __restrict__ wsel)
{
  const int wv=threadIdx.x>>6, lane=threadIdx.x&63;
  const int row=blockIdx.x*4+wv;
  const float* xr=x+(size_t)row*1024;
  const float* hr=h+(size_t)row*1024;
  float xv[16], h0[8], h1[8];
  #pragma unroll
  for(int j=0;j<16;++j) xv[j]=xr[j*64+lane];
  #pragma unroll
  for(int j=0;j<8;++j){ h0[j]=hr[j*64+lane]; h1[j]=hr[512+j*64+lane]; }
  float spec[6];
  #pragma unroll
  for(int e=0;e<6;++e){
    float s=0.f;
    #pragma unroll
    for(int j=0;j<16;++j) s+=xv[j]*esp[e*1024+j*64+lane];
    #pragma unroll
    for(int j=0;j<8;++j) s+=h0[j]*w2s[e*512+j*64+lane];
    s=wred(s);
    spec[e]=1.f/(1.f+__expf(-(s+b2s[e])));
  }
  #pragma unroll
  for(int e=0;e<6;++e){
    const float se=spec[e];
    #pragma unroll
    for(int j=0;j<8;++j) h1[j]+=se*rw1t[e*512+j*64+lane];
  }
  #pragma unroll
  for(int j=0;j<8;++j) h1[j]=fmaxf(h1[j],0.f);
  float p[6];
  float m=-1e30f;
  #pragma unroll
  for(int e=0;e<6;++e){
    float s=0.f;
    #pragma unroll
    for(int j=0;j<8;++j) s+=h1[j]*w2r[e*512+j*64+lane];
    p[e]=wred(s)+b2r[e];
    m=fmaxf(m,p[e]);
  }
  float den=0.f;
  #pragma unroll
  for(int e=0;e<6;++e){ p[e]=__expf(p[e]-m); den+=p[e]; }
  float invd=1.f/den;
  #pragma unroll
  for(int e=0;e<6;++e) p[e]*=invd;
  if(lane==0){
    const int k=*kint;
    float w[6]={0,0,0,0,0,0};
    bool used[6]={false,false,false,false,false,false};
    int idx[4]; float val[4];
    #pragma unroll
    for(int j=0;j<4;++j){
      int bi=0; float bv=-1e30f;
      #pragma unroll
      for(int e=0;e<6;++e) if(!used[e] && p[e]>bv){ bv=p[e]; bi=e; }
      used[bi]=true; idx[j]=bi; val[j]=bv;
    }
    float mm=val[0], dd=0.f, g[4]={0,0,0,0};
    for(int j=0;j<k;++j){ g[j]=__expf(val[j]-mm); dd+=g[j]; }
    for(int j=0;j<k;++j) w[idx[j]]=g[j]/dd;
    float* o=&wsel[(size_t)row*6];
    o[0]=w[0]; o[1]=w[1]; o[2]=w[2]; o[3]=w[3]; o[4]=w[4]; o[5]=w[5];
  }
}

// ---------------- CrossField expert: MFMA, 1 wave/row, bf16 x (x_hi), wave-local LDS ----
// per-wave LDS region; only the shared weight load needs a barrier.
__global__ __launch_bounds__(256) void cf_kernel(const u16* __restrict__ xh,
    const float* __restrict__ w_in, const float* __restrict__ b_in,
    const float* __restrict__ w_o, const float* __restrict__ b_o,
    const float* __restrict__ w_f, const float* __restrict__ b_f,
    const float* __restrict__ wsel, u16* __restrict__ comb){
  __shared__ __align__(16) u16 smem[6400 + 4*5120];
  const int tid=threadIdx.x, wv=tid>>6, lane=tid&63;
  const int fr=lane&15, fq=lane>>4;
  for(int i=tid;i<5120;i+=256){
    float v=(i<3072)? w_in[i] : (i<4096? w_o[i-3072] : w_f[i-4096]);
    smem[(i>>5)*40 + (i&31)] = f2bf(v);
  }
  u16* wb   = smem + 6400 + wv*5120;
  u16* xbf  = wb;            // 32 fields x 40 (bf16 x)
  u16* bufA = wb + 1280;
  u16* bufB = bufA + 1280;
  u16* bufC = bufB + 1280;
  const int row = blockIdx.x*4 + wv;
  const u16* xr = xh + (size_t)row*1024;
  #pragma unroll
  for(int t=0;t<4;++t){
    u16x4 v = ((const u16x4*)xr)[t*64+lane];
    int e=(t*64+lane)*4;
    *(u16x4*)&xbf[(e>>5)*40 + (e&31)] = v;
  }
  __syncthreads();
  short8 xa[2];
  #pragma unroll
  for(int ft=0;ft<2;++ft) xa[ft]=*(const short8*)&xbf[(ft*16+fr)*40 + fq*8];
  f32x4 acc1[2][6];
  #pragma unroll
  for(int ct=0;ct<6;++ct){
    short8 wfrag=*(const short8*)&smem[(ct*16+fr)*40 + fq*8];
    #pragma unroll
    for(int ft=0;ft<2;++ft)
      acc1[ft][ct]=__builtin_amdgcn_mfma_f32_16x16x32_bf16(xa[ft],wfrag,(f32x4)0.f,0,0,0);
  }
  float bi[6];
  #pragma unroll
  for(int ct=0;ct<6;++ct) bi[ct]=b_in[ct*16+fr];
  #pragma unroll
  for(int ct=0;ct<6;++ct){
    #pragma unroll
    for(int ft=0;ft<2;++ft){
      #pragma unroll
      for(int j=0;j<4;++j){
        u16 h=f2bf(acc1[ft][ct][j]+bi[ct]);
        int rg=ft*16+fq*4+j, cg=ct*16+fr;
        if(cg<32)      bufA[rg*40+cg]=h;
        else if(cg<64) bufB[rg*40+(cg-32)]=h;
        else           bufC[(cg-64)*40+rg]=h;
      }
    }
  }
  short8 qa0=*(const short8*)&bufA[fr*40+fq*8];
  short8 qa1=*(const short8*)&bufA[(16+fr)*40+fq*8];
  short8 kb0=*(const short8*)&bufB[fr*40+fq*8];
  short8 kb1=*(const short8*)&bufB[(16+fr)*40+fq*8];
  f32x4 aS[2][2];
  aS[0][0]=__builtin_amdgcn_mfma_f32_16x16x32_bf16(qa0,kb0,(f32x4)0.f,0,0,0);
  aS[0][1]=__builtin_amdgcn_mfma_f32_16x16x32_bf16(qa0,kb1,(f32x4)0.f,0,0,0);
  aS[1][0]=__builtin_amdgcn_mfma_f32_16x16x32_bf16(qa1,kb0,(f32x4)0.f,0,0,0);
  aS[1][1]=__builtin_amdgcn_mfma_f32_16x16x32_bf16(qa1,kb1,(f32x4)0.f,0,0,0);
  const float scale=0.17677669529663687f;
  #pragma unroll
  for(int rt=0;rt<2;++rt){
    #pragma unroll
    for(int j=0;j<4;++j){
      float e0=aS[rt][0][j]*scale, e1=aS[rt][1][j]*scale;
      float m=fmaxf(e0,e1);
      #pragma unroll
      for(int o=1;o<16;o<<=1) m=fmaxf(m,__shfl_xor(m,o));
      e0=__expf(e0-m); e1=__expf(e1-m);
      float den=e0+e1;
      #pragma unroll
      for(int o=1;o<16;o<<=1) den+=__shfl_xor(den,o);
      float inv=1.f/den;
      bufA[(rt*16+fq*4+j)*40 + fr]      = f2bf(e0*inv);
      bufA[(rt*16+fq*4+j)*40 + 16+fr]   = f2bf(e1*inv);
    }
  }
  short8 pa0=*(const short8*)&bufA[fr*40+fq*8];
  short8 pa1=*(const short8*)&bufA[(16+fr)*40+fq*8];
  short8 vb0=*(const short8*)&bufC[fr*40+fq*8];
  short8 vb1=*(const short8*)&bufC[(16+fr)*40+fq*8];
  f32x4 aA[2][2];
  aA[0][0]=__builtin_amdgcn_mfma_f32_16x16x32_bf16(pa0,vb0,(f32x4)0.f,0,0,0);
  aA[0][1]=__builtin_amdgcn_mfma_f32_16x16x32_bf16(pa0,vb1,(f32x4)0.f,0,0,0);
  aA[1][0]=__builtin_amdgcn_mfma_f32_16x16x32_bf16(pa1,vb0,(f32x4)0.f,0,0,0);
  aA[1][1]=__builtin_amdgcn_mfma_f32_16x16x32_bf16(pa1,vb1,(f32x4)0.f,0,0,0);
  #pragma unroll
  for(int rt=0;rt<2;++rt)
    #pragma unroll
    for(int dt=0;dt<2;++dt)
      #pragma unroll
      for(int j=0;j<4;++j)
        bufB[(rt*16+fq*4+j)*40 + dt*16+fr]=f2bf(aA[rt][dt][j]);
  short8 aa0=*(const short8*)&bufB[fr*40+fq*8];
  short8 aa1=*(const short8*)&bufB[(16+fr)*40+fq*8];
  short8 ob0=*(const short8*)&smem[(96+fr)*40+fq*8];
  short8 ob1=*(const short8*)&smem[(112+fr)*40+fq*8];
  f32x4 aF[2][2];
  aF[0][0]=__builtin_amdgcn_mfma_f32_16x16x32_bf16(aa0,ob0,(f32x4)0.f,0,0,0);
  aF[0][1]=__builtin_amdgcn_mfma_f32_16x16x32_bf16(aa0,ob1,(f32x4)0.f,0,0,0);
  aF[1][0]=__builtin_amdgcn_mfma_f32_16x16x32_bf16(aa1,ob0,(f32x4)0.f,0,0,0);
  aF[1][1]=__builtin_amdgcn_mfma_f32_16x16x32_bf16(aa1,ob1,(f32x4)0.f,0,0,0);
  float bo[2]={b_o[fr], b_o[16+fr]};
  #pragma unroll
  for(int rt=0;rt<2;++rt){
    #pragma unroll
    for(int dt=0;dt<2;++dt){
      #pragma unroll
      for(int j=0;j<4;++j){
        int fld=rt*16+fq*4+j, d=dt*16+fr;
        float attf=aF[rt][dt][j]+bo[dt];
        bufC[fld*40+d]=f2bf(attf*bf2f(xbf[fld*40+d]));
      }
    }
  }
  short8 pr0=*(const short8*)&bufC[fr*40+fq*8];
  short8 pr1=*(const short8*)&bufC[(16+fr)*40+fq*8];
  short8 fb0=*(const short8*)&smem[(128+fr)*40+fq*8];
  short8 fb1=*(const short8*)&smem[(144+fr)*40+fq*8];
  f32x4 aE[2][2];
  aE[0][0]=__builtin_amdgcn_mfma_f32_16x16x32_bf16(pr0,fb0,(f32x4)0.f,0,0,0);
  aE[0][1]=__builtin_amdgcn_mfma_f32_16x16x32_bf16(pr0,fb1,(f32x4)0.f,0,0,0);
  aE[1][0]=__builtin_amdgcn_mfma_f32_16x16x32_bf16(pr1,fb0,(f32x4)0.f,0,0,0);
  aE[1][1]=__builtin_amdgcn_mfma_f32_16x16x32_bf16(pr1,fb1,(f32x4)0.f,0,0,0);
  float bff[2]={b_f[fr], b_f[16+fr]};
  const float w2=wsel[row*6+2];
  u16* cb=&comb[(size_t)row*1024];
  #pragma unroll
  for(int rt=0;rt<2;++rt){
    #pragma unroll
    for(int dt=0;dt<2;++dt){
      #pragma unroll
      for(int j=0;j<4;++j){
        int fld=rt*16+fq*4+j, d=dt*16+fr;
        u16 old=cb[fld*32+d];
        cb[fld*32+d]=f2bf(bf2f(old)+w2*(aE[rt][dt][j]+bff[dt]));
      }
    }
  }
}

// ---------------- Temporal expert + final bf16 conversion (bf16 comb, f32 x) -----------
__global__ __launch_bounds__(256) void tp_kernel(const float* __restrict__ x,
    const float* __restrict__ wsel, const u16* __restrict__ comb,
    const float* __restrict__ tcw, const float* __restrict__ tcb,
    const float* __restrict__ tfw, const float* __restrict__ tfb,
    u16* __restrict__ obf){
  __shared__ float xs[1026];
  const int row=blockIdx.x, tid=threadIdx.x;
  f32x4 u=((const f32x4*)(x+(size_t)row*1024))[tid];
  #pragma unroll
  for(int j=0;j<4;++j) xs[1+4*tid+j]=u[j];
  if(tid==0){ xs[0]=0.f; xs[1025]=0.f; }
  __syncthreads();
  const float w4=wsel[row*6+4];
  float tc[4][3], tb[4], tf[4];
  #pragma unroll
  for(int o=0;o<4;++o){
    #pragma unroll
    for(int kh=0;kh<3;++kh) tc[o][kh]=tcw[o*3+kh];
    tb[o]=tcb[o]; tf[o]=tfw[o];
  }
  const float tfb0=tfb[0];
  u16x4 cv=((const u16x4*)(comb+(size_t)row*1024))[tid];
  u16x4 ov;
  #pragma unroll
  for(int j=0;j<4;++j){
    const int d=4*tid+j;
    float pre=tfb0;
    #pragma unroll
    for(int o=0;o<4;++o){
      float c=tb[o]+tc[o][0]*xs[d]+tc[o][1]*xs[d+1]+tc[o][2]*xs[d+2];
      pre+=tf[o]*fmaxf(c,0.f);
    }
    float wt=1.f/(1.f+__expf(-pre));
    float xv=xs[1+d];
    ov[j]=f2bf(bf2f(cv[j])+w4*xv*xv*wt);
  }
  ((u16x4*)(obf+(size_t)row*1024))[tid]=ov;
}

// =======================================================================================
extern "C" void kernel_launch(void* const* d_in, const int* in_sizes, int n_in,
                              void* d_out, int out_size, void* d_ws, size_t ws_size,
                              hipStream_t stream)
{
  const float* x     =(const float*)d_in[0];
  const float* esp   =(const float*)d_in[1];
  const float* sim_w1=(const float*)d_in[2],  *sim_b1=(const float*)d_in[3];
  const float* sim_w2=(const float*)d_in[4],  *sim_b2=(const float*)d_in[5];
  const float* rout_w1=(const float*)d_in[6], *rout_b1=(const float*)d_in[7];
  const float* rout_w2=(const float*)d_in[8], *rout_b2=(const float*)d_in[9];
  const float* kw1=(const float*)d_in[10], *kb1=(const float*)d_in[11];
  const float* kw2=(const float*)d_in[12], *kb2=(const float*)d_in[13];
  const float* spv_w=(const float*)d_in[14], *spv_b=(const float*)d_in[15];
  const float* spo_w=(const float*)d_in[16], *spo_b=(const float*)d_in[17];
  const float* spq1_w=(const float*)d_in[18], *spq1_b=(const float*)d_in[19];
  const float* spq2_w=(const float*)d_in[20], *spq2_b=(const float*)d_in[21];
  const float* de_w1=(const float*)d_in[22], *de_b1=(const float*)d_in[23];
  const float* de_w2=(const float*)d_in[24], *de_b2=(const float*)d_in[25];
  const float* de_gw=(const float*)d_in[26], *de_gb=(const float*)d_in[27];
  const float* cf_inw=(const float*)d_in[28], *cf_inb=(const float*)d_in[29];
  const float* cf_ow=(const float*)d_in[30], *cf_ob=(const float*)d_in[31];
  const float* cf_fw=(const float*)d_in[32], *cf_fb=(const float*)d_in[33];
  const float* hf_w1=(const float*)d_in[34], *hf_b1=(const float*)d_in[35];
  const float* hf_w2=(const float*)d_in[36], *hf_b2=(const float*)d_in[37];
  const float* tc_w=(const float*)d_in[38], *tc_b=(const float*)d_in[39];
  const float* tf_w=(const float*)d_in[40], *tf_b=(const float*)d_in[41];
  const float* lt_w1=(const float*)d_in[42], *lt_b1=(const float*)d_in[43];
  const float* lt_w2=(const float*)d_in[44], *lt_b2=(const float*)d_in[45];
  const float* op_w=(const float*)d_in[46], *op_b=(const float*)d_in[47];
  float* out=(float*)d_out;
  (void)in_sizes; (void)n_in; (void)out_size; (void)ws_size;

  constexpr int NB=8192;
  const size_t BD=(size_t)NB*1024;
  char* base=(char*)d_ws; size_t off=0;
  auto carve=[&](size_t n)->void*{ void* q=base+off; off+=(n+255)&~(size_t)255; return q; };
  u16*  comb =(u16*)carve(BD*2);
  u16*  bufA =(u16*)carve(BD*2);
  u16*  bufB =(u16*)carve(BD*2);
  u16*  x_hi =(u16*)carve(BD*2);
  u16*  x_lo =(u16*)carve(BD*2);
  float* h1024=(float*)carve(BD*4);
  u16*  h768 =(u16*)carve((size_t)NB*768*2);
  u16* w1024h=(u16*)carve((size_t)1024*1024*2);
  u16* w1024l=(u16*)carve((size_t)1024*1024*2);
  u16* spv_bf =(u16*)carve((size_t)1024*1024*2);
  u16* spo_bf =(u16*)carve((size_t)1024*1024*2);
  u16* spq1_bf=(u16*)carve((size_t)1024*1024*2);
  u16* spq2_bf=(u16*)carve((size_t)1024*1024*2);
  u16* w768_bf=(u16*)carve((size_t)768*1024*2);
  u16* dew2_bf=(u16*)carve((size_t)1024*256*2);
  u16* degw_bf=(u16*)carve((size_t)1024*1024*2);
  u16* hfw2_bf=(u16*)carve((size_t)1024*256*2);
  u16* ltw2_bf=(u16*)carve((size_t)1024*256*2);
  u16* opw_bf =(u16*)carve((size_t)1024*1024*2);
  u16* spvT_bf=(u16*)carve((size_t)1024*1024*2);
  float* bc   =(float*)carve((size_t)1024*4);
  float* b768 =(float*)carve((size_t)768*4);
  float* b1024=(float*)carve((size_t)1024*4);
  float* rw1t =(float*)carve((size_t)3072*4);
  float* wsel=(float*)carve((size_t)NB*6*4);
  float* kvals=(float*)carve((size_t)NB*4);
  int*   kint=(int*)carve(256);

  const dim3 blk(256);
  auto cgrid=[&](int n4)->dim3{ int g=(n4+255)/256; return dim3(g>2048?2048:g); };

  // ---- feats + x split (x read once) ----
  feats_kernel<<<dim3(2048),blk,0,stream>>>(x, kw1,kb1,kw2,kb2, kvals, x_hi, x_lo);
  median_kernel<<<dim3(1),blk,0,stream>>>(kvals, kint);

  // ---- weight conversions (batched; spv_bf is produced by the compose GEMM below) ----
  cvt_split<<<cgrid(131072),blk,0,stream>>>(sim_w1, w1024h, w1024l, 131072);
  cvt_split_rw1<<<cgrid(131072),blk,0,stream>>>(rout_w1, w1024h+524288, w1024l+524288);
  cvt5_kernel<<<cgrid(5*262144),blk,0,stream>>>(spo_w,spq1_w,spq2_w,de_gw,op_w,
                                                spo_bf,spq1_bf,spq2_bf,degw_bf,opw_bf, 262144);
  cvt6_kernel<<<cgrid(6*65536),blk,0,stream>>>(de_w1,de_w2,hf_w1,hf_w2,lt_w1,lt_w2,
                                               w768_bf,dew2_bf,w768_bf+262144,hfw2_bf,w768_bf+524288,ltw2_bf, 65536);
  transpose_bf<<<dim3(1024),blk,0,stream>>>(spv_w, spvT_bf);
  small_pack<<<dim3(260),blk,0,stream>>>(spo_w, spv_b, spo_b, de_b1, hf_b1, lt_b1,
                                         sim_b1, rout_b1, rout_w1, bc, b768, b1024, rw1t);

  // ---- routing pipeline (merged N=1024 split GEMM + fused router) ----
  gemm_split2<<<dim3(512),blk,0,stream>>>(x_hi,x_lo, w1024h,w1024l, b1024, h1024, NB,1024,1024);
  router_kernel<<<dim3(2048),blk,0,stream>>>(x, h1024, esp, sim_w2, sim_b2, rw1t, rout_w2, rout_b2, kint, wsel);

  // ---- compose Wc = spo_w @ spv_w, bf16 written directly (EPI0) ----
  gemm_bt<0,0><<<dim3(8,8),blk,0,stream>>>(spo_bf, spvT_bf, nullptr, nullptr, nullptr, nullptr, nullptr, spv_bf, nullptr, 1024,1024,1024,1024);

  // ---- expert 0: SparseQuadratic (3 GEMMs via composition) ----
  gemm_bt<0,2><<<dim3(8,64),blk,0,stream>>>(x_hi, spv_bf, bc, x_hi, nullptr, nullptr, nullptr, bufB, nullptr, NB,1024,1024,1024);
  gemm_bt<1,0><<<dim3(8,64),blk,0,stream>>>(bufB, spq1_bf, spq1_b, nullptr, nullptr, nullptr, nullptr, bufA, nullptr, NB,1024,1024,1024);
  gemm_bt<0,3><<<dim3(8,64),blk,0,stream>>>(bufA, spq2_bf, spq2_b, nullptr, nullptr, wsel, comb, nullptr, nullptr, NB,1024,1024,1024);

  // ---- merged first layers: h768 = act768(x @ [de_w1;hf_w1;lt_w1]^T + b768) ----
  gemm_bt<5,0><<<dim3(6,64),blk,0,stream>>>(x_hi, w768_bf, b768, nullptr, nullptr, nullptr, nullptr, h768, nullptr, NB,768,1024,1024);

  // ---- expert 1: DenseQuadratic ----
  gemm_bt<2,0><<<dim3(8,64),blk,0,stream>>>(x_hi, degw_bf, de_gb, nullptr, nullptr, nullptr, nullptr, bufB, nullptr, NB,1024,1024,1024);
  gemm_bt<0,4><<<dim3(8,64),blk,0,stream>>>(h768, dew2_bf, de_b2, bufB, nullptr, wsel, comb, nullptr, x_hi, NB,1024,256,768);

  // ---- expert 2: CrossField (MFMA, fused accumulate, bf16 x) ----
  cf_kernel<<<dim3(2048),blk,0,stream>>>(x_hi, cf_inw, cf_inb, cf_ow, cf_ob, cf_fw, cf_fb, wsel, comb);

  // ---- expert 3: HighFreq ----
  gemm_bt<0,5><<<dim3(8,64),blk,0,stream>>>(h768+256, hfw2_bf, hf_b2, x_hi, nullptr, wsel, comb, nullptr, nullptr, NB,1024,256,768);

  // ---- expert 5: LongTail ----
  gemm_bt<0,6><<<dim3(8,64),blk,0,stream>>>(h768+512, ltw2_bf, lt_b2, x_hi, nullptr, wsel, comb, nullptr, nullptr, NB,1024,256,768);

  // ---- expert 4: Temporal (last comb reader) + final bf16 conversion ----
  tp_kernel<<<dim3(NB),blk,0,stream>>>(x, wsel, comb, tc_w, tc_b, tf_w, tf_b, bufB);

  // ---- output projection + residual (f32 out) ----
  gemm_bt<0,7><<<dim3(8,64),blk,0,stream>>>(bufB, opw_bf, op_b, nullptr, x, nullptr, nullptr, out, nullptr, NB,1024,1024,1024);
}